// Round 2
// baseline (595.803 us; speedup 1.0000x reference)
//
#include <hip/hip_runtime.h>
#include <stdint.h>
#include <stddef.h>

#define T_SEQ 2048
#define DIM   4096
#define NH    32
#define NKV   8
#define HD    128
#define KVD   (NKV*HD)   // 1024

typedef __attribute__((ext_vector_type(8))) short short8;
typedef __attribute__((ext_vector_type(4))) float floatx4;

static __device__ __forceinline__ float bf2f(short u) {
    union { unsigned int i; float f; } c; c.i = ((unsigned int)(unsigned short)u) << 16; return c.f;
}
static __device__ __forceinline__ short f2bf(float f) {
    union { float f; unsigned int u; } c; c.f = f;
    unsigned int r = c.u + 0x7fff + ((c.u >> 16) & 1);
    return (short)(r >> 16);
}
static __device__ __forceinline__ short8 ld8_f2b(const float* p) {
    floatx4 a = *(const floatx4*)p;
    floatx4 b = *(const floatx4*)(p + 4);
    short8 r;
    r[0]=f2bf(a[0]); r[1]=f2bf(a[1]); r[2]=f2bf(a[2]); r[3]=f2bf(a[3]);
    r[4]=f2bf(b[0]); r[5]=f2bf(b[1]); r[6]=f2bf(b[2]); r[7]=f2bf(b[3]);
    return r;
}

// async 16B global->LDS (m97 pattern; LDS dest is wave-uniform-base + lane*16)
#define GLD16(g, l) __builtin_amdgcn_global_load_lds( \
    (const __attribute__((address_space(1))) unsigned int*)(g), \
    (__attribute__((address_space(3))) unsigned int*)(l), 16, 0, 0)

// DPP cross-lane (within 16-lane row): xor1/xor2/xor4/xor8 butterflies, VALU-speed
template<int CTRL>
static __device__ __forceinline__ float dppf(float x) {
    return __int_as_float(__builtin_amdgcn_update_dpp(
        0, __float_as_int(x), CTRL, 0xf, 0xf, true));
}
static __device__ __forceinline__ float rowmax16(float x) {
    x = fmaxf(x, dppf<0xB1>(x));    // quad_perm(1,0,3,2)  xor 1
    x = fmaxf(x, dppf<0x4E>(x));    // quad_perm(2,3,0,1)  xor 2
    x = fmaxf(x, dppf<0x141>(x));   // row_half_mirror     xor 4
    x = fmaxf(x, dppf<0x140>(x));   // row_mirror          xor 8
    return x;
}
static __device__ __forceinline__ float rowsum16(float x) {
    x += dppf<0xB1>(x);
    x += dppf<0x4E>(x);
    x += dppf<0x141>(x);
    x += dppf<0x140>(x);
    return x;
}

// ---------------------------------------------------------------------------
// fp32 -> bf16 bulk convert: x (8M), wk (4M), wv (4M), wo (16M); 8 elems/thread
// ---------------------------------------------------------------------------
__global__ __launch_bounds__(256)
void cvt_bf16(const float* __restrict__ x, const float* __restrict__ wk,
              const float* __restrict__ wv, const float* __restrict__ wo,
              short* __restrict__ xb, short* __restrict__ wkb,
              short* __restrict__ wvb, short* __restrict__ wob) {
    size_t i8 = ((size_t)blockIdx.x * 256 + threadIdx.x) * 8;
    const float* src; short* dst; size_t off;
    if (i8 < 8388608)        { src = x;  dst = xb;  off = i8; }
    else if (i8 < 12582912)  { src = wk; dst = wkb; off = i8 - 8388608; }
    else if (i8 < 16777216)  { src = wv; dst = wvb; off = i8 - 12582912; }
    else                     { src = wo; dst = wob; off = i8 - 16777216; }
    *(short8*)(dst + off) = ld8_f2b(src + off);
}

// ---------------------------------------------------------------------------
// out init: out[t, :] = bias  (fp32), vectorized float4. Runs early; the
// split-K out-GEMM atomically accumulates on top.
// ---------------------------------------------------------------------------
__global__ __launch_bounds__(256)
void bias_init(const float* __restrict__ b, float* __restrict__ out) {
    size_t i = (size_t)blockIdx.x * 256 + threadIdx.x;   // one float4 each
    int col4 = (int)((i * 4) & (DIM - 1));
    floatx4 v;
    v[0] = b[col4]; v[1] = b[col4+1]; v[2] = b[col4+2]; v[3] = b[col4+3];
    *(floatx4*)(out + i * 4) = v;
}

// ---------------------------------------------------------------------------
// m97-style GEMM core: C[M,N] = A[M,K]*B[N,K]^T (+ bias). bf16 A/B via
// global_load_lds dwordx4; 128x128 tile, BK=32, 4 waves 2x2.
// LD = row stride of A and B (elements); K = contraction length (<= LD for
// split-K). CMODE: 0 = bf16 store (+bias), 1 = f32 store (+bias),
// 2 = f32 atomicAdd (no bias — pre-initialized).
// ---------------------------------------------------------------------------
template<int CMODE>
static __device__ __forceinline__
void gemm_core(const short* __restrict__ A, const short* __restrict__ B,
               const float* __restrict__ bias, void* __restrict__ Cp,
               int N, int K, int LD, int bm, int bn) {
    __shared__ short sA[128*32];
    __shared__ short sB[128*32];
    const int tid  = threadIdx.x;
    const int wave = tid >> 6, lane = tid & 63;
    const int l15  = lane & 15, lq = lane >> 4;
    const int wm   = (wave >> 1) * 64, wn = (wave & 1) * 64;

    floatx4 acc[4][4];
    #pragma unroll
    for (int i = 0; i < 4; i++)
        #pragma unroll
        for (int j = 0; j < 4; j++)
            acc[i][j] = (floatx4)(0.0f);

    // staging map: chunk c -> lds elem c*8 (lane-linear, 16B/lane)
    const int c0 = tid, c1 = 256 + tid;
    const int r0 = c0 >> 2, k0 = (c0 & 3) * 8;
    const int r1 = c1 >> 2, k1 = (c1 & 3) * 8;
    const short* pA0 = A + (size_t)(bm + r0) * LD + k0;
    const short* pA1 = A + (size_t)(bm + r1) * LD + k1;
    const short* pB0 = B + (size_t)(bn + r0) * LD + k0;
    const short* pB1 = B + (size_t)(bn + r1) * LD + k1;

    for (int kt = 0; kt < K; kt += 32) {
        __syncthreads();
        GLD16(pA0 + kt, &sA[c0 * 8]);
        GLD16(pA1 + kt, &sA[c1 * 8]);
        GLD16(pB0 + kt, &sB[c0 * 8]);
        GLD16(pB1 + kt, &sB[c1 * 8]);
        __syncthreads();   // drains vmcnt before barrier

        short8 af[4], bfr[4];
        #pragma unroll
        for (int mi = 0; mi < 4; mi++)
            af[mi] = *(const short8*)&sA[(wm + mi*16 + l15)*32 + lq*8];
        #pragma unroll
        for (int ni = 0; ni < 4; ni++)
            bfr[ni] = *(const short8*)&sB[(wn + ni*16 + l15)*32 + lq*8];
        #pragma unroll
        for (int mi = 0; mi < 4; mi++)
            #pragma unroll
            for (int ni = 0; ni < 4; ni++)
                acc[mi][ni] = __builtin_amdgcn_mfma_f32_16x16x32_bf16(af[mi], bfr[ni], acc[mi][ni], 0, 0, 0);
    }

    // epilogue: C/D layout col=lane&15, row=(lane>>4)*4+reg  [m89/m91]
    #pragma unroll
    for (int ni = 0; ni < 4; ni++) {
        int col = bn + wn + ni*16 + l15;
        float bv = (CMODE == 2) ? 0.0f : bias[col];
        #pragma unroll
        for (int mi = 0; mi < 4; mi++) {
            int row = bm + wm + mi*16 + lq*4;
            #pragma unroll
            for (int r = 0; r < 4; r++) {
                float v = acc[mi][ni][r] + bv;
                if (CMODE == 1)      ((float*)Cp)[(size_t)(row + r)*N + col] = v;
                else if (CMODE == 0) ((short*)Cp)[(size_t)(row + r)*N + col] = f2bf(v);
                else atomicAdd(&((float*)Cp)[(size_t)(row + r)*N + col], v);
            }
        }
    }
}

// Fused Q/K/V projections, one dispatch: grid (48, 16) = 768 blocks (3/CU).
// ct<32 -> Q (wob), ct<40 -> K (wkb), else V (wvb). All read the same A (xb).
// Note: 48 % 8 == 0, so all 16 row-blocks of one B-panel land on one XCD L2.
__global__ __launch_bounds__(256)
void gemm_qkv(const short* __restrict__ A,
              const short* __restrict__ Bq, const float* __restrict__ bq, short* __restrict__ Cq,
              const short* __restrict__ Bk, const float* __restrict__ bk, short* __restrict__ Ck,
              const short* __restrict__ Bv, const float* __restrict__ bv, short* __restrict__ Cv) {
    const int ct = blockIdx.x;
    const short* B; const float* bias; short* C; int N, bn;
    if (ct < 32)      { B = Bq; bias = bq; C = Cq; N = DIM; bn = ct*128; }
    else if (ct < 40) { B = Bk; bias = bk; C = Ck; N = KVD; bn = (ct-32)*128; }
    else              { B = Bv; bias = bv; C = Cv; N = KVD; bn = (ct-40)*128; }
    gemm_core<0>(A, B, bias, C, N, DIM, DIM, blockIdx.y * 128, bn);
}

// Out-projection, split-K x2: grid (32, 16, 2) = 1024 blocks (4/CU).
// z selects K-half; fp32 atomicAdd onto bias-initialized out.
__global__ __launch_bounds__(256)
void gemm_out_sk(const short* __restrict__ A, const short* __restrict__ B,
                 float* __restrict__ Cp) {
    const int kh = blockIdx.z;
    gemm_core<2>(A + kh*(DIM/2), B + kh*(DIM/2), nullptr, Cp,
                 DIM, DIM/2, DIM, blockIdx.y * 128, blockIdx.x * 128);
}

// ---------------------------------------------------------------------------
// RoPE in-place on bf16 Q (T,NH,HD) and K (T,NKV,HD); freqs fp32
// ---------------------------------------------------------------------------
__global__ __launch_bounds__(256)
void rope_k(short* __restrict__ Q, short* __restrict__ Kc,
            const float* __restrict__ fc, const float* __restrict__ fs) {
    int idx = blockIdx.x * 256 + threadIdx.x;
    const int NQ = T_SEQ * NH  * (HD/2);
    const int NK = T_SEQ * NKV * (HD/2);
    short* base; int t, i; size_t off;
    if (idx < NQ) {
        i = idx & 63;
        int th = idx >> 6;
        t = th >> 5;
        off = (size_t)th * HD + i*2;
        base = Q;
    } else if (idx < NQ + NK) {
        int kidx = idx - NQ;
        i = kidx & 63;
        int th = kidx >> 6;
        t = th >> 3;
        off = (size_t)th * HD + i*2;
        base = Kc;
    } else return;
    float re = bf2f(base[off]), im = bf2f(base[off+1]);
    float c = fc[t*64 + i], s = fs[t*64 + i];
    base[off]   = f2bf(re*c - im*s);
    base[off+1] = f2bf(re*s + im*c);
}

// ---------------------------------------------------------------------------
// V[T,KVD] -> Vt[KVD,T]  (64x64 LDS tiles)
// ---------------------------------------------------------------------------
__global__ __launch_bounds__(256)
void vtrans(const short* __restrict__ V, short* __restrict__ Vt) {
    __shared__ short sT[64*72];
    const int tid = threadIdx.x;
    const int bt = blockIdx.x, bd = blockIdx.y;
    #pragma unroll
    for (int i = 0; i < 2; i++) {
        int c = i*256 + tid;
        int r = c >> 3, c8 = (c & 7) * 8;
        *(short8*)&sT[r*72 + c8] = *(const short8*)(V + (size_t)(bt*64 + r)*KVD + bd*64 + c8);
    }
    __syncthreads();
    #pragma unroll
    for (int i = 0; i < 2; i++) {
        int c = i*256 + tid;
        int d = c >> 3, t8 = (c & 7) * 8;
        short8 o;
        #pragma unroll
        for (int j = 0; j < 8; j++) o[j] = sT[(t8 + j)*72 + d];
        *(short8*)(Vt + (size_t)(bd*64 + d)*T_SEQ + bt*64 + t8) = o;
    }
}

// ---------------------------------------------------------------------------
// Causal flash attention, kv-grouped: grid (64, 8), block 256 (4 waves).
// Block = (32 q-rows) x (4 heads of one kv group); wave w = head w.
// qt remap: co-resident blocks (id, id+256) get q-tiles (u, 63-u) -> each
// CU's combined work ~33 iterations (causal balance). 52KB LDS -> 2-3
// blocks/CU with INDEPENDENT barriers (cross-block latency hiding).
// Q frags loaded direct from global (no sQ). Softmax reductions via DPP
// (no ds_swizzle). Defer-max rescale (T13, THR=8). Mask on diagonal tile
// only. setprio(1) around MFMA clusters (T5).
// ---------------------------------------------------------------------------
#define ROWK 136
#define ROWV 72

__global__ __launch_bounds__(256, 2)
void flash_attn(const short* __restrict__ Q, const short* __restrict__ Kc,
                const short* __restrict__ Vt, short* __restrict__ O) {
    __shared__ short sK[64*ROWK];
    __shared__ short sV[128*ROWV];    // sV[d][k]
    __shared__ short sP[4*2048];      // per-wave 32x64 strip
    const int tid  = threadIdx.x;
    const int wave = tid >> 6, lane = tid & 63;
    const int l15  = lane & 15, lq = lane >> 4;
    const int kvg  = blockIdx.y;
    const int qt   = (blockIdx.y < 4) ? (int)blockIdx.x : 63 - (int)blockIdx.x;
    const int hl   = wave;               // head_local 0..3
    const int qb   = qt * 32;
    const float scale = 0.08838834764831845f;  // 1/sqrt(128)

    // Q fragments direct from global: wave's 32 q-rows x 128 d -> 32 VGPRs
    short8 qf[2][4];
    #pragma unroll
    for (int mi = 0; mi < 2; mi++)
        #pragma unroll
        for (int ks = 0; ks < 4; ks++)
            qf[mi][ks] = *(const short8*)(Q + (size_t)(qb + mi*16 + l15)*DIM
                                          + kvg*512 + hl*128 + ks*32 + lq*8);

    short* sPw = sP + wave*2048;

    float m_r[2][4], l_r[2][4];
    floatx4 o_acc[2][8];
    #pragma unroll
    for (int mi = 0; mi < 2; mi++) {
        #pragma unroll
        for (int r = 0; r < 4; r++) { m_r[mi][r] = -1e30f; l_r[mi][r] = 0.0f; }
        #pragma unroll
        for (int nd = 0; nd < 8; nd++) o_acc[mi][nd] = (floatx4)(0.0f);
    }

    const int ktmax = qt >> 1;
    for (int kt = 0; kt <= ktmax; kt++) {
        // issue staging loads early: global only, overlaps the barrier wait
        short8 kbuf[4], vbuf[4];
        #pragma unroll
        for (int i = 0; i < 4; i++) {
            int c = i*256 + tid;
            int r = c >> 4, c8 = (c & 15) * 8;
            kbuf[i] = *(const short8*)(Kc + (size_t)(kt*64 + r)*KVD + kvg*HD + c8);
            int rv = c >> 3, v8 = (c & 7) * 8;
            vbuf[i] = *(const short8*)(Vt + (size_t)(kvg*HD + rv)*T_SEQ + kt*64 + v8);
        }
        __syncthreads();   // prev-iter sK/sV reads done
        #pragma unroll
        for (int i = 0; i < 4; i++) {
            int c = i*256 + tid;
            int r = c >> 4, c8 = (c & 15) * 8;
            *(short8*)&sK[r*ROWK + c8] = kbuf[i];
            int rv = c >> 3, v8 = (c & 7) * 8;
            *(short8*)&sV[rv*ROWV + v8] = vbuf[i];
        }
        __syncthreads();

        // S = Q K^T: 32q x 64k, K=128 (kf read shared across mi)
        floatx4 s_acc[2][4];
        #pragma unroll
        for (int mi = 0; mi < 2; mi++)
            #pragma unroll
            for (int ni = 0; ni < 4; ni++) s_acc[mi][ni] = (floatx4)(0.0f);
        __builtin_amdgcn_s_setprio(1);
        #pragma unroll
        for (int ks = 0; ks < 4; ks++)
            #pragma unroll
            for (int ni = 0; ni < 4; ni++) {
                short8 kf = *(const short8*)&sK[(ni*16 + l15)*ROWK + ks*32 + lq*8];
                s_acc[0][ni] = __builtin_amdgcn_mfma_f32_16x16x32_bf16(qf[0][ks], kf, s_acc[0][ni], 0, 0, 0);
                s_acc[1][ni] = __builtin_amdgcn_mfma_f32_16x16x32_bf16(qf[1][ks], kf, s_acc[1][ni], 0, 0, 0);
            }
        __builtin_amdgcn_s_setprio(0);

        const bool last = (kt == ktmax);

        // scale (+mask on diagonal tile) + online softmax with defer-max
        #pragma unroll
        for (int mi = 0; mi < 2; mi++) {
            float sv[4][4], mx[4];
            #pragma unroll
            for (int r = 0; r < 4; r++) mx[r] = -1e30f;
            #pragma unroll
            for (int ni = 0; ni < 4; ni++) {
                int col = kt*64 + ni*16 + l15;
                #pragma unroll
                for (int r = 0; r < 4; r++) {
                    float x = s_acc[mi][ni][r] * scale;
                    if (last) {
                        int row = qb + mi*16 + lq*4 + r;
                        x = (col <= row) ? x : -1e30f;
                    }
                    sv[ni][r] = x;
                    mx[r] = fmaxf(mx[r], x);
                }
            }
            #pragma unroll
            for (int r = 0; r < 4; r++) mx[r] = rowmax16(mx[r]);  // DPP, VALU-only

            // defer-max: only rescale when tile max grew past THR=8
            float g = fmaxf(fmaxf(mx[0] - m_r[mi][0], mx[1] - m_r[mi][1]),
                            fmaxf(mx[2] - m_r[mi][2], mx[3] - m_r[mi][3]));
            if (__any(g > 8.0f)) {
                #pragma unroll
                for (int r = 0; r < 4; r++) {
                    float mn = fmaxf(m_r[mi][r], mx[r]);
                    float a  = __expf(m_r[mi][r] - mn);
                    m_r[mi][r] = mn;
                    l_r[mi][r] *= a;
                    #pragma unroll
                    for (int nd = 0; nd < 8; nd++) o_acc[mi][nd][r] *= a;
                }
            }

            float rs[4] = {0.0f, 0.0f, 0.0f, 0.0f};
            #pragma unroll
            for (int ni = 0; ni < 4; ni++)
                #pragma unroll
                for (int r = 0; r < 4; r++) {
                    float p = __expf(sv[ni][r] - m_r[mi][r]);   // bounded by e^8
                    sv[ni][r] = p;
                    rs[r] += p;
                }
            #pragma unroll
            for (int r = 0; r < 4; r++) {
                rs[r] = rowsum16(rs[r]);                        // DPP, VALU-only
                l_r[mi][r] += rs[r];
            }

            // P strip -> own-wave LDS (C->A layout), chunk-XOR swizzle
            #pragma unroll
            for (int ni = 0; ni < 4; ni++)
                #pragma unroll
                for (int r = 0; r < 4; r++) {
                    int q = mi*16 + lq*4 + r, k = ni*16 + l15;
                    sPw[q*64 + (((k >> 3) ^ (q & 7))*8) + (k & 7)] = f2bf(sv[ni][r]);
                }
        }
        // no barrier: sP strip is wave-private (lgkmcnt ordering within wave)

        // O += P V (contraction over 64 keys; vf read shared across mi)
        __builtin_amdgcn_s_setprio(1);
        #pragma unroll
        for (int ks = 0; ks < 2; ks++) {
            int kk = ks*32 + lq*8;
            short8 pf[2];
            #pragma unroll
            for (int mi = 0; mi < 2; mi++) {
                int q = mi*16 + l15;
                pf[mi] = *(const short8*)&sPw[q*64 + (((kk >> 3) ^ (q & 7))*8)];
            }
            #pragma unroll
            for (int nd = 0; nd < 8; nd++) {
                short8 vf = *(const short8*)&sV[(nd*16 + l15)*ROWV + kk];
                o_acc[0][nd] = __builtin_amdgcn_mfma_f32_16x16x32_bf16(pf[0], vf, o_acc[0][nd], 0, 0, 0);
                o_acc[1][nd] = __builtin_amdgcn_mfma_f32_16x16x32_bf16(pf[1], vf, o_acc[1][nd], 0, 0, 0);
            }
        }
        __builtin_amdgcn_s_setprio(0);
    }

    // epilogue
    #pragma unroll
    for (int mi = 0; mi < 2; mi++)
        #pragma unroll
        for (int nd = 0; nd < 8; nd++) {
            int col = (kvg*4 + hl)*HD + nd*16 + l15;
            #pragma unroll
            for (int r = 0; r < 4; r++) {
                int row = qb + mi*16 + lq*4 + r;
                O[(size_t)row*DIM + col] = f2bf(o_acc[mi][nd][r] / l_r[mi][r]);
            }
        }
}

// ---------------------------------------------------------------------------
extern "C" void kernel_launch(void* const* d_in, const int* in_sizes, int n_in,
                              void* d_out, int out_size, void* d_ws, size_t ws_size,
                              hipStream_t stream) {
    const float* x    = (const float*)d_in[0];
    const float* fc   = (const float*)d_in[1];
    const float* fs   = (const float*)d_in[2];
    // d_in[3] mask: causal, analytic. d_in[4,5] caches: dead (pos=0).
    const float* wk_w = (const float*)d_in[6];
    const float* wk_b = (const float*)d_in[7];
    const float* wv_w = (const float*)d_in[8];
    const float* wv_b = (const float*)d_in[9];
    const float* wo_w = (const float*)d_in[10];
    const float* wo_b = (const float*)d_in[11];
    float* out = (float*)d_out;

    short* xb  = (short*)d_ws;                 //  8388608
    short* wkb = xb  + 8388608;                //  4194304
    short* wvb = wkb + 4194304;                //  4194304
    short* wob = wvb + 4194304;                // 16777216
    short* Q   = wob + 16777216;               //  8388608
    short* K   = Q   + 8388608;                //  2097152
    short* V   = K   + 2097152;                //  2097152
    short* Vt  = V   + 2097152;                //  2097152
    short* AO  = Vt  + 2097152;                //  8388608  (total ~113.4 MB)

    cvt_bf16<<<dim3(16384), dim3(256), 0, stream>>>(x, wk_w, wv_w, wo_w, xb, wkb, wvb, wob);

    // out = bias rows (split-K out-GEMM accumulates atomically on top)
    bias_init<<<dim3(T_SEQ*DIM/4/256), dim3(256), 0, stream>>>(wo_b, out);

    // fused Q/K/V projections (reference quirk: q is projected with wo_w/wo_b)
    gemm_qkv<<<dim3(48, 16), dim3(256), 0, stream>>>(
        xb, wob, wo_b, Q, wkb, wk_b, K, wvb, wv_b, V);

    int nrope = T_SEQ*NH*(HD/2) + T_SEQ*NKV*(HD/2);
    rope_k<<<dim3((nrope + 255)/256), dim3(256), 0, stream>>>(Q, K, fc, fs);

    vtrans<<<dim3(32, 16), dim3(256), 0, stream>>>(V, Vt);

    flash_attn<<<dim3(64, 8), dim3(256), 0, stream>>>(Q, K, Vt, AO);

    gemm_out_sk<<<dim3(32, 16, 2), dim3(256), 0, stream>>>(AO, wob, out);
}

// Round 3
// 530.326 us; speedup vs baseline: 1.1235x; 1.1235x over previous
//
#include <hip/hip_runtime.h>
#include <stdint.h>
#include <stddef.h>

#define T_SEQ 2048
#define DIM   4096
#define NH    32
#define NKV   8
#define HD    128
#define KVD   (NKV*HD)   // 1024

typedef __attribute__((ext_vector_type(8))) short short8;
typedef __attribute__((ext_vector_type(4))) float floatx4;

static __device__ __forceinline__ float bf2f(short u) {
    union { unsigned int i; float f; } c; c.i = ((unsigned int)(unsigned short)u) << 16; return c.f;
}
static __device__ __forceinline__ short f2bf(float f) {
    union { float f; unsigned int u; } c; c.f = f;
    unsigned int r = c.u + 0x7fff + ((c.u >> 16) & 1);
    return (short)(r >> 16);
}
static __device__ __forceinline__ short8 ld8_f2b(const float* p) {
    floatx4 a = *(const floatx4*)p;
    floatx4 b = *(const floatx4*)(p + 4);
    short8 r;
    r[0]=f2bf(a[0]); r[1]=f2bf(a[1]); r[2]=f2bf(a[2]); r[3]=f2bf(a[3]);
    r[4]=f2bf(b[0]); r[5]=f2bf(b[1]); r[6]=f2bf(b[2]); r[7]=f2bf(b[3]);
    return r;
}

// async 16B global->LDS (m97 pattern; LDS dest is wave-uniform-base + lane*16)
#define GLD16(g, l) __builtin_amdgcn_global_load_lds( \
    (const __attribute__((address_space(1))) unsigned int*)(g), \
    (__attribute__((address_space(3))) unsigned int*)(l), 16, 0, 0)

// DPP cross-lane (within 16-lane row): xor1/xor2/xor4/xor8 butterflies, VALU-speed
template<int CTRL>
static __device__ __forceinline__ float dppf(float x) {
    return __int_as_float(__builtin_amdgcn_update_dpp(
        0, __float_as_int(x), CTRL, 0xf, 0xf, true));
}
static __device__ __forceinline__ float rowmax16(float x) {
    x = fmaxf(x, dppf<0xB1>(x));    // quad_perm(1,0,3,2)  xor 1
    x = fmaxf(x, dppf<0x4E>(x));    // quad_perm(2,3,0,1)  xor 2
    x = fmaxf(x, dppf<0x141>(x));   // row_half_mirror     xor 4
    x = fmaxf(x, dppf<0x140>(x));   // row_mirror          xor 8
    return x;
}
static __device__ __forceinline__ float rowsum16(float x) {
    x += dppf<0xB1>(x);
    x += dppf<0x4E>(x);
    x += dppf<0x141>(x);
    x += dppf<0x140>(x);
    return x;
}

// ---------------------------------------------------------------------------
// fp32 -> bf16 bulk convert: x (8M), wk (4M), wv (4M), wo (16M); 8 elems/thread
// ---------------------------------------------------------------------------
__global__ __launch_bounds__(256)
void cvt_bf16(const float* __restrict__ x, const float* __restrict__ wk,
              const float* __restrict__ wv, const float* __restrict__ wo,
              short* __restrict__ xb, short* __restrict__ wkb,
              short* __restrict__ wvb, short* __restrict__ wob) {
    size_t i8 = ((size_t)blockIdx.x * 256 + threadIdx.x) * 8;
    const float* src; short* dst; size_t off;
    if (i8 < 8388608)        { src = x;  dst = xb;  off = i8; }
    else if (i8 < 12582912)  { src = wk; dst = wkb; off = i8 - 8388608; }
    else if (i8 < 16777216)  { src = wv; dst = wvb; off = i8 - 12582912; }
    else                     { src = wo; dst = wob; off = i8 - 16777216; }
    *(short8*)(dst + off) = ld8_f2b(src + off);
}

// ---------------------------------------------------------------------------
// 2-phase (T3-minimum) GEMM core: C[M,N] = A[M,K]*B[N,K]^T + bias.
// Double-buffered LDS (4 distinct arrays -> compile-time buffer select);
// next-tile global_load_lds issued BEFORE current-tile compute, single
// __syncthreads per K-step (its implicit vmcnt(0) waits on loads issued a
// full compute phase earlier -> latency hidden). 128x128 tile, BK=32,
// 4 waves 2x2.
// ---------------------------------------------------------------------------
template<bool C_F32>
static __device__ __forceinline__
void gemm_core(const short* __restrict__ A, const short* __restrict__ B,
               const float* __restrict__ bias, void* __restrict__ Cp,
               int N, int K, int bm, int bn) {
    __shared__ short sA0[128*32];
    __shared__ short sA1[128*32];
    __shared__ short sB0[128*32];
    __shared__ short sB1[128*32];
    const int tid  = threadIdx.x;
    const int wave = tid >> 6, lane = tid & 63;
    const int l15  = lane & 15, lq = lane >> 4;
    const int wm   = (wave >> 1) * 64, wn = (wave & 1) * 64;

    floatx4 acc[4][4];
    #pragma unroll
    for (int i = 0; i < 4; i++)
        #pragma unroll
        for (int j = 0; j < 4; j++)
            acc[i][j] = (floatx4)(0.0f);

    // staging map: chunk c -> lds elem c*8 (lane-linear, 16B/lane)
    const int c0 = tid, c1 = 256 + tid;
    const int r0 = c0 >> 2, k0 = (c0 & 3) * 8;
    const int r1 = c1 >> 2, k1 = (c1 & 3) * 8;
    const short* pA0 = A + (size_t)(bm + r0) * K + k0;
    const short* pA1 = A + (size_t)(bm + r1) * K + k1;
    const short* pB0 = B + (size_t)(bn + r0) * K + k0;
    const short* pB1 = B + (size_t)(bn + r1) * K + k1;

    auto stage = [&](short* dA, short* dB, int kt) {
        GLD16(pA0 + kt, dA + c0 * 8);
        GLD16(pA1 + kt, dA + c1 * 8);
        GLD16(pB0 + kt, dB + c0 * 8);
        GLD16(pB1 + kt, dB + c1 * 8);
    };
    auto compute = [&](const short* dA, const short* dB) {
        short8 af[4], bfr[4];
        #pragma unroll
        for (int mi = 0; mi < 4; mi++)
            af[mi] = *(const short8*)&dA[(wm + mi*16 + l15)*32 + lq*8];
        #pragma unroll
        for (int ni = 0; ni < 4; ni++)
            bfr[ni] = *(const short8*)&dB[(wn + ni*16 + l15)*32 + lq*8];
        #pragma unroll
        for (int mi = 0; mi < 4; mi++)
            #pragma unroll
            for (int ni = 0; ni < 4; ni++)
                acc[mi][ni] = __builtin_amdgcn_mfma_f32_16x16x32_bf16(af[mi], bfr[ni], acc[mi][ni], 0, 0, 0);
    };

    // prologue: fill buf0 with tile 0
    stage(sA0, sB0, 0);
    __syncthreads();                 // implicit vmcnt(0) drains prologue loads

    const int nt = K >> 5;           // K-steps (even: K multiple of 64)
    for (int t = 0; t < nt; t += 2) {
        // step A: prefetch tile t+1 -> buf1, compute tile t from buf0
        stage(sA1, sB1, (t + 1) * 32);
        compute(sA0, sB0);
        __syncthreads();             // vmcnt(0): buf1 loads had full compute to fly
        // step B: prefetch tile t+2 -> buf0, compute tile t+1 from buf1
        if (t + 2 < nt) stage(sA0, sB0, (t + 2) * 32);
        compute(sA1, sB1);
        __syncthreads();
    }

    // epilogue: C/D layout col=lane&15, row=(lane>>4)*4+reg  [m89/m91]
    #pragma unroll
    for (int ni = 0; ni < 4; ni++) {
        int col = bn + wn + ni*16 + l15;
        float bv = bias[col];
        #pragma unroll
        for (int mi = 0; mi < 4; mi++) {
            int row = bm + wm + mi*16 + lq*4;
            #pragma unroll
            for (int r = 0; r < 4; r++) {
                float v = acc[mi][ni][r] + bv;
                if (C_F32) ((float*)Cp)[(size_t)(row + r)*N + col] = v;
                else       ((short*)Cp)[(size_t)(row + r)*N + col] = f2bf(v);
            }
        }
    }
}

template<bool C_F32>
__global__ __launch_bounds__(256)
void gemm_bt(const short* __restrict__ A, const short* __restrict__ B,
             const float* __restrict__ bias, void* __restrict__ Cp,
             int N, int K) {
    gemm_core<C_F32>(A, B, bias, Cp, N, K, blockIdx.y * 128, blockIdx.x * 128);
}

// K and V projections fused into one dispatch (z selects), 256 blocks total
__global__ __launch_bounds__(256)
void gemm_kv(const short* __restrict__ A,
             const short* __restrict__ Bk, const float* __restrict__ bk, short* __restrict__ Ck,
             const short* __restrict__ Bv, const float* __restrict__ bv, short* __restrict__ Cv) {
    const short* B = blockIdx.z ? Bv : Bk;
    const float* bias = blockIdx.z ? bv : bk;
    short* C = blockIdx.z ? Cv : Ck;
    gemm_core<false>(A, B, bias, C, KVD, DIM, blockIdx.y * 128, blockIdx.x * 128);
}

// ---------------------------------------------------------------------------
// RoPE in-place on bf16 Q (T,NH,HD) and K (T,NKV,HD); freqs fp32
// ---------------------------------------------------------------------------
__global__ __launch_bounds__(256)
void rope_k(short* __restrict__ Q, short* __restrict__ Kc,
            const float* __restrict__ fc, const float* __restrict__ fs) {
    int idx = blockIdx.x * 256 + threadIdx.x;
    const int NQ = T_SEQ * NH  * (HD/2);
    const int NK = T_SEQ * NKV * (HD/2);
    short* base; int t, i; size_t off;
    if (idx < NQ) {
        i = idx & 63;
        int th = idx >> 6;
        t = th >> 5;
        off = (size_t)th * HD + i*2;
        base = Q;
    } else if (idx < NQ + NK) {
        int kidx = idx - NQ;
        i = kidx & 63;
        int th = kidx >> 6;
        t = th >> 3;
        off = (size_t)th * HD + i*2;
        base = Kc;
    } else return;
    float re = bf2f(base[off]), im = bf2f(base[off+1]);
    float c = fc[t*64 + i], s = fs[t*64 + i];
    base[off]   = f2bf(re*c - im*s);
    base[off+1] = f2bf(re*s + im*c);
}

// ---------------------------------------------------------------------------
// V[T,KVD] -> Vt[KVD,T]  (64x64 LDS tiles)
// ---------------------------------------------------------------------------
__global__ __launch_bounds__(256)
void vtrans(const short* __restrict__ V, short* __restrict__ Vt) {
    __shared__ short sT[64*72];
    const int tid = threadIdx.x;
    const int bt = blockIdx.x, bd = blockIdx.y;
    #pragma unroll
    for (int i = 0; i < 2; i++) {
        int c = i*256 + tid;
        int r = c >> 3, c8 = (c & 7) * 8;
        *(short8*)&sT[r*72 + c8] = *(const short8*)(V + (size_t)(bt*64 + r)*KVD + bd*64 + c8);
    }
    __syncthreads();
    #pragma unroll
    for (int i = 0; i < 2; i++) {
        int c = i*256 + tid;
        int d = c >> 3, t8 = (c & 7) * 8;
        short8 o;
        #pragma unroll
        for (int j = 0; j < 8; j++) o[j] = sT[(t8 + j)*72 + d];
        *(short8*)(Vt + (size_t)(bd*64 + d)*T_SEQ + bt*64 + t8) = o;
    }
}

// ---------------------------------------------------------------------------
// Causal flash attention, kv-grouped: grid (64, 8), block 256 (4 waves).
// Block = (32 q-rows) x (4 heads of one kv group); wave w = head w.
// qt remap: co-resident blocks (id, id+256) get q-tiles (u, 63-u) -> each
// CU's combined work ~33 iterations (causal balance). 52KB LDS -> 2-3
// blocks/CU with INDEPENDENT barriers (cross-block latency hiding).
// Q frags loaded direct from global (no sQ). Softmax reductions via DPP
// (no ds_swizzle). Defer-max rescale (T13, THR=8). Mask on diagonal tile
// only. setprio(1) around MFMA clusters (T5).
// ---------------------------------------------------------------------------
#define ROWK 136
#define ROWV 72

__global__ __launch_bounds__(256, 2)
void flash_attn(const short* __restrict__ Q, const short* __restrict__ Kc,
                const short* __restrict__ Vt, short* __restrict__ O) {
    __shared__ short sK[64*ROWK];
    __shared__ short sV[128*ROWV];    // sV[d][k]
    __shared__ short sP[4*2048];      // per-wave 32x64 strip
    const int tid  = threadIdx.x;
    const int wave = tid >> 6, lane = tid & 63;
    const int l15  = lane & 15, lq = lane >> 4;
    const int kvg  = blockIdx.y;
    const int qt   = (blockIdx.y < 4) ? (int)blockIdx.x : 63 - (int)blockIdx.x;
    const int hl   = wave;               // head_local 0..3
    const int qb   = qt * 32;
    const float scale = 0.08838834764831845f;  // 1/sqrt(128)

    // Q fragments direct from global: wave's 32 q-rows x 128 d -> 32 VGPRs
    short8 qf[2][4];
    #pragma unroll
    for (int mi = 0; mi < 2; mi++)
        #pragma unroll
        for (int ks = 0; ks < 4; ks++)
            qf[mi][ks] = *(const short8*)(Q + (size_t)(qb + mi*16 + l15)*DIM
                                          + kvg*512 + hl*128 + ks*32 + lq*8);

    short* sPw = sP + wave*2048;

    float m_r[2][4], l_r[2][4];
    floatx4 o_acc[2][8];
    #pragma unroll
    for (int mi = 0; mi < 2; mi++) {
        #pragma unroll
        for (int r = 0; r < 4; r++) { m_r[mi][r] = -1e30f; l_r[mi][r] = 0.0f; }
        #pragma unroll
        for (int nd = 0; nd < 8; nd++) o_acc[mi][nd] = (floatx4)(0.0f);
    }

    const int ktmax = qt >> 1;
    for (int kt = 0; kt <= ktmax; kt++) {
        // issue staging loads early: global only, overlaps the barrier wait
        short8 kbuf[4], vbuf[4];
        #pragma unroll
        for (int i = 0; i < 4; i++) {
            int c = i*256 + tid;
            int r = c >> 4, c8 = (c & 15) * 8;
            kbuf[i] = *(const short8*)(Kc + (size_t)(kt*64 + r)*KVD + kvg*HD + c8);
            int rv = c >> 3, v8 = (c & 7) * 8;
            vbuf[i] = *(const short8*)(Vt + (size_t)(kvg*HD + rv)*T_SEQ + kt*64 + v8);
        }
        __syncthreads();   // prev-iter sK/sV reads done
        #pragma unroll
        for (int i = 0; i < 4; i++) {
            int c = i*256 + tid;
            int r = c >> 4, c8 = (c & 15) * 8;
            *(short8*)&sK[r*ROWK + c8] = kbuf[i];
            int rv = c >> 3, v8 = (c & 7) * 8;
            *(short8*)&sV[rv*ROWV + v8] = vbuf[i];
        }
        __syncthreads();

        // S = Q K^T: 32q x 64k, K=128 (kf read shared across mi)
        floatx4 s_acc[2][4];
        #pragma unroll
        for (int mi = 0; mi < 2; mi++)
            #pragma unroll
            for (int ni = 0; ni < 4; ni++) s_acc[mi][ni] = (floatx4)(0.0f);
        __builtin_amdgcn_s_setprio(1);
        #pragma unroll
        for (int ks = 0; ks < 4; ks++)
            #pragma unroll
            for (int ni = 0; ni < 4; ni++) {
                short8 kf = *(const short8*)&sK[(ni*16 + l15)*ROWK + ks*32 + lq*8];
                s_acc[0][ni] = __builtin_amdgcn_mfma_f32_16x16x32_bf16(qf[0][ks], kf, s_acc[0][ni], 0, 0, 0);
                s_acc[1][ni] = __builtin_amdgcn_mfma_f32_16x16x32_bf16(qf[1][ks], kf, s_acc[1][ni], 0, 0, 0);
            }
        __builtin_amdgcn_s_setprio(0);

        const bool last = (kt == ktmax);

        // scale (+mask on diagonal tile) + online softmax with defer-max
        #pragma unroll
        for (int mi = 0; mi < 2; mi++) {
            float sv[4][4], mx[4];
            #pragma unroll
            for (int r = 0; r < 4; r++) mx[r] = -1e30f;
            #pragma unroll
            for (int ni = 0; ni < 4; ni++) {
                int col = kt*64 + ni*16 + l15;
                #pragma unroll
                for (int r = 0; r < 4; r++) {
                    float x = s_acc[mi][ni][r] * scale;
                    if (last) {
                        int row = qb + mi*16 + lq*4 + r;
                        x = (col <= row) ? x : -1e30f;
                    }
                    sv[ni][r] = x;
                    mx[r] = fmaxf(mx[r], x);
                }
            }
            #pragma unroll
            for (int r = 0; r < 4; r++) mx[r] = rowmax16(mx[r]);  // DPP, VALU-only

            // defer-max: only rescale when tile max grew past THR=8
            float g = fmaxf(fmaxf(mx[0] - m_r[mi][0], mx[1] - m_r[mi][1]),
                            fmaxf(mx[2] - m_r[mi][2], mx[3] - m_r[mi][3]));
            if (__any(g > 8.0f)) {
                #pragma unroll
                for (int r = 0; r < 4; r++) {
                    float mn = fmaxf(m_r[mi][r], mx[r]);
                    float a  = __expf(m_r[mi][r] - mn);
                    m_r[mi][r] = mn;
                    l_r[mi][r] *= a;
                    #pragma unroll
                    for (int nd = 0; nd < 8; nd++) o_acc[mi][nd][r] *= a;
                }
            }

            float rs[4] = {0.0f, 0.0f, 0.0f, 0.0f};
            #pragma unroll
            for (int ni = 0; ni < 4; ni++)
                #pragma unroll
                for (int r = 0; r < 4; r++) {
                    float p = __expf(sv[ni][r] - m_r[mi][r]);   // bounded by e^8
                    sv[ni][r] = p;
                    rs[r] += p;
                }
            #pragma unroll
            for (int r = 0; r < 4; r++) {
                rs[r] = rowsum16(rs[r]);                        // DPP, VALU-only
                l_r[mi][r] += rs[r];
            }

            // P strip -> own-wave LDS (C->A layout), chunk-XOR swizzle
            #pragma unroll
            for (int ni = 0; ni < 4; ni++)
                #pragma unroll
                for (int r = 0; r < 4; r++) {
                    int q = mi*16 + lq*4 + r, k = ni*16 + l15;
                    sPw[q*64 + (((k >> 3) ^ (q & 7))*8) + (k & 7)] = f2bf(sv[ni][r]);
                }
        }
        // no barrier: sP strip is wave-private (lgkmcnt ordering within wave)

        // O += P V (contraction over 64 keys; vf read shared across mi)
        __builtin_amdgcn_s_setprio(1);
        #pragma unroll
        for (int ks = 0; ks < 2; ks++) {
            int kk = ks*32 + lq*8;
            short8 pf[2];
            #pragma unroll
            for (int mi = 0; mi < 2; mi++) {
                int q = mi*16 + l15;
                pf[mi] = *(const short8*)&sPw[q*64 + (((kk >> 3) ^ (q & 7))*8)];
            }
            #pragma unroll
            for (int nd = 0; nd < 8; nd++) {
                short8 vf = *(const short8*)&sV[(nd*16 + l15)*ROWV + kk];
                o_acc[0][nd] = __builtin_amdgcn_mfma_f32_16x16x32_bf16(pf[0], vf, o_acc[0][nd], 0, 0, 0);
                o_acc[1][nd] = __builtin_amdgcn_mfma_f32_16x16x32_bf16(pf[1], vf, o_acc[1][nd], 0, 0, 0);
            }
        }
        __builtin_amdgcn_s_setprio(0);
    }

    // epilogue
    #pragma unroll
    for (int mi = 0; mi < 2; mi++)
        #pragma unroll
        for (int nd = 0; nd < 8; nd++) {
            int col = (kvg*4 + hl)*HD + nd*16 + l15;
            #pragma unroll
            for (int r = 0; r < 4; r++) {
                int row = qb + mi*16 + lq*4 + r;
                O[(size_t)row*DIM + col] = f2bf(o_acc[mi][nd][r] / l_r[mi][r]);
            }
        }
}

// ---------------------------------------------------------------------------
extern "C" void kernel_launch(void* const* d_in, const int* in_sizes, int n_in,
                              void* d_out, int out_size, void* d_ws, size_t ws_size,
                              hipStream_t stream) {
    const float* x    = (const float*)d_in[0];
    const float* fc   = (const float*)d_in[1];
    const float* fs   = (const float*)d_in[2];
    // d_in[3] mask: causal, analytic. d_in[4,5] caches: dead (pos=0).
    const float* wk_w = (const float*)d_in[6];
    const float* wk_b = (const float*)d_in[7];
    const float* wv_w = (const float*)d_in[8];
    const float* wv_b = (const float*)d_in[9];
    const float* wo_w = (const float*)d_in[10];
    const float* wo_b = (const float*)d_in[11];
    float* out = (float*)d_out;

    short* xb  = (short*)d_ws;                 //  8388608
    short* wkb = xb  + 8388608;                //  4194304
    short* wvb = wkb + 4194304;                //  4194304
    short* wob = wvb + 4194304;                // 16777216
    short* Q   = wob + 16777216;               //  8388608
    short* K   = Q   + 8388608;                //  2097152
    short* V   = K   + 2097152;                //  2097152
    short* Vt  = V   + 2097152;                //  2097152
    short* AO  = Vt  + 2097152;                //  8388608  (total ~113.4 MB)

    cvt_bf16<<<dim3(16384), dim3(256), 0, stream>>>(x, wk_w, wv_w, wo_w, xb, wkb, wvb, wob);

    // reference quirk: q is projected with wo_w/wo_b
    gemm_bt<false><<<dim3(32, 16), dim3(256), 0, stream>>>(xb, wob, wo_b, Q, DIM, DIM);
    gemm_kv<<<dim3(8, 16, 2), dim3(256), 0, stream>>>(xb, wkb, wk_b, K, wvb, wv_b, V);

    int nrope = T_SEQ*NH*(HD/2) + T_SEQ*NKV*(HD/2);
    rope_k<<<dim3((nrope + 255)/256), dim3(256), 0, stream>>>(Q, K, fc, fs);

    vtrans<<<dim3(32, 16), dim3(256), 0, stream>>>(V, Vt);

    flash_attn<<<dim3(64, 8), dim3(256), 0, stream>>>(Q, K, Vt, AO);

    gemm_bt<true><<<dim3(32, 16), dim3(256), 0, stream>>>(AO, wob, wo_b, out, DIM, DIM);
}

// Round 4
// 519.002 us; speedup vs baseline: 1.1480x; 1.0218x over previous
//
#include <hip/hip_runtime.h>
#include <stdint.h>
#include <stddef.h>

#define T_SEQ 2048
#define DIM   4096
#define NH    32
#define NKV   8
#define HD    128
#define KVD   (NKV*HD)   // 1024

typedef __attribute__((ext_vector_type(8))) short short8;
typedef __attribute__((ext_vector_type(4))) float floatx4;

static __device__ __forceinline__ float bf2f(short u) {
    union { unsigned int i; float f; } c; c.i = ((unsigned int)(unsigned short)u) << 16; return c.f;
}
static __device__ __forceinline__ short f2bf(float f) {
    union { float f; unsigned int u; } c; c.f = f;
    unsigned int r = c.u + 0x7fff + ((c.u >> 16) & 1);
    return (short)(r >> 16);
}
static __device__ __forceinline__ short8 ld8_f2b(const float* p) {
    floatx4 a = *(const floatx4*)p;
    floatx4 b = *(const floatx4*)(p + 4);
    short8 r;
    r[0]=f2bf(a[0]); r[1]=f2bf(a[1]); r[2]=f2bf(a[2]); r[3]=f2bf(a[3]);
    r[4]=f2bf(b[0]); r[5]=f2bf(b[1]); r[6]=f2bf(b[2]); r[7]=f2bf(b[3]);
    return r;
}

// async 16B global->LDS (m97 pattern; LDS dest is wave-uniform-base + lane*16)
#define GLD16(g, l) __builtin_amdgcn_global_load_lds( \
    (const __attribute__((address_space(1))) unsigned int*)(g), \
    (__attribute__((address_space(3))) unsigned int*)(l), 16, 0, 0)

// DPP cross-lane (within 16-lane row): xor1/xor2/xor4/xor8 butterflies, VALU-speed
template<int CTRL>
static __device__ __forceinline__ float dppf(float x) {
    return __int_as_float(__builtin_amdgcn_update_dpp(
        0, __float_as_int(x), CTRL, 0xf, 0xf, true));
}
static __device__ __forceinline__ float rowmax16(float x) {
    x = fmaxf(x, dppf<0xB1>(x));    // quad_perm(1,0,3,2)  xor 1
    x = fmaxf(x, dppf<0x4E>(x));    // quad_perm(2,3,0,1)  xor 2
    x = fmaxf(x, dppf<0x141>(x));   // row_half_mirror     xor 4
    x = fmaxf(x, dppf<0x140>(x));   // row_mirror          xor 8
    return x;
}
static __device__ __forceinline__ float rowsum16(float x) {
    x += dppf<0xB1>(x);
    x += dppf<0x4E>(x);
    x += dppf<0x141>(x);
    x += dppf<0x140>(x);
    return x;
}

// ---------------------------------------------------------------------------
// fp32 -> bf16 bulk convert: x (8M), wk (4M), wv (4M), wo (16M); 8 elems/thread
// ---------------------------------------------------------------------------
__global__ __launch_bounds__(256)
void cvt_bf16(const float* __restrict__ x, const float* __restrict__ wk,
              const float* __restrict__ wv, const float* __restrict__ wo,
              short* __restrict__ xb, short* __restrict__ wkb,
              short* __restrict__ wvb, short* __restrict__ wob) {
    size_t i8 = ((size_t)blockIdx.x * 256 + threadIdx.x) * 8;
    const float* src; short* dst; size_t off;
    if (i8 < 8388608)        { src = x;  dst = xb;  off = i8; }
    else if (i8 < 12582912)  { src = wk; dst = wkb; off = i8 - 8388608; }
    else if (i8 < 16777216)  { src = wv; dst = wvb; off = i8 - 12582912; }
    else                     { src = wo; dst = wob; off = i8 - 16777216; }
    *(short8*)(dst + off) = ld8_f2b(src + off);
}

// ---------------------------------------------------------------------------
// 2-phase (T3-minimum) GEMM core: C[M,N] = A[M,K]*B[N,K]^T + bias.
// Double-buffered LDS; next-tile global_load_lds issued BEFORE current-tile
// compute, single __syncthreads per K-step. 128x128 tile, BK=32, 4 waves 2x2.
// ---------------------------------------------------------------------------
template<bool C_F32>
static __device__ __forceinline__
void gemm_core(const short* __restrict__ A, const short* __restrict__ B,
               const float* __restrict__ bias, void* __restrict__ Cp,
               int N, int K, int bm, int bn) {
    __shared__ short sA0[128*32];
    __shared__ short sA1[128*32];
    __shared__ short sB0[128*32];
    __shared__ short sB1[128*32];
    const int tid  = threadIdx.x;
    const int wave = tid >> 6, lane = tid & 63;
    const int l15  = lane & 15, lq = lane >> 4;
    const int wm   = (wave >> 1) * 64, wn = (wave & 1) * 64;

    floatx4 acc[4][4];
    #pragma unroll
    for (int i = 0; i < 4; i++)
        #pragma unroll
        for (int j = 0; j < 4; j++)
            acc[i][j] = (floatx4)(0.0f);

    // staging map: chunk c -> lds elem c*8 (lane-linear, 16B/lane)
    const int c0 = tid, c1 = 256 + tid;
    const int r0 = c0 >> 2, k0 = (c0 & 3) * 8;
    const int r1 = c1 >> 2, k1 = (c1 & 3) * 8;
    const short* pA0 = A + (size_t)(bm + r0) * K + k0;
    const short* pA1 = A + (size_t)(bm + r1) * K + k1;
    const short* pB0 = B + (size_t)(bn + r0) * K + k0;
    const short* pB1 = B + (size_t)(bn + r1) * K + k1;

    auto stage = [&](short* dA, short* dB, int kt) {
        GLD16(pA0 + kt, dA + c0 * 8);
        GLD16(pA1 + kt, dA + c1 * 8);
        GLD16(pB0 + kt, dB + c0 * 8);
        GLD16(pB1 + kt, dB + c1 * 8);
    };
    auto compute = [&](const short* dA, const short* dB) {
        short8 af[4], bfr[4];
        #pragma unroll
        for (int mi = 0; mi < 4; mi++)
            af[mi] = *(const short8*)&dA[(wm + mi*16 + l15)*32 + lq*8];
        #pragma unroll
        for (int ni = 0; ni < 4; ni++)
            bfr[ni] = *(const short8*)&dB[(wn + ni*16 + l15)*32 + lq*8];
        #pragma unroll
        for (int mi = 0; mi < 4; mi++)
            #pragma unroll
            for (int ni = 0; ni < 4; ni++)
                acc[mi][ni] = __builtin_amdgcn_mfma_f32_16x16x32_bf16(af[mi], bfr[ni], acc[mi][ni], 0, 0, 0);
    };

    // prologue: fill buf0 with tile 0
    stage(sA0, sB0, 0);
    __syncthreads();                 // implicit vmcnt(0) drains prologue loads

    const int nt = K >> 5;           // K-steps (even: K multiple of 64)
    for (int t = 0; t < nt; t += 2) {
        // step A: prefetch tile t+1 -> buf1, compute tile t from buf0
        stage(sA1, sB1, (t + 1) * 32);
        compute(sA0, sB0);
        __syncthreads();             // vmcnt(0): buf1 loads had full compute to fly
        // step B: prefetch tile t+2 -> buf0, compute tile t+1 from buf1
        if (t + 2 < nt) stage(sA0, sB0, (t + 2) * 32);
        compute(sA1, sB1);
        __syncthreads();
    }

    // epilogue: C/D layout col=lane&15, row=(lane>>4)*4+reg  [m89/m91]
    #pragma unroll
    for (int ni = 0; ni < 4; ni++) {
        int col = bn + wn + ni*16 + l15;
        float bv = bias[col];
        #pragma unroll
        for (int mi = 0; mi < 4; mi++) {
            int row = bm + wm + mi*16 + lq*4;
            #pragma unroll
            for (int r = 0; r < 4; r++) {
                float v = acc[mi][ni][r] + bv;
                if (C_F32) ((float*)Cp)[(size_t)(row + r)*N + col] = v;
                else       ((short*)Cp)[(size_t)(row + r)*N + col] = f2bf(v);
            }
        }
    }
}

template<bool C_F32>
__global__ __launch_bounds__(256)
void gemm_bt(const short* __restrict__ A, const short* __restrict__ B,
             const float* __restrict__ bias, void* __restrict__ Cp,
             int N, int K) {
    gemm_core<C_F32>(A, B, bias, Cp, N, K, blockIdx.y * 128, blockIdx.x * 128);
}

// K and V projections fused into one dispatch (z selects), 256 blocks total
__global__ __launch_bounds__(256)
void gemm_kv(const short* __restrict__ A,
             const short* __restrict__ Bk, const float* __restrict__ bk, short* __restrict__ Ck,
             const short* __restrict__ Bv, const float* __restrict__ bv, short* __restrict__ Cv) {
    const short* B = blockIdx.z ? Bv : Bk;
    const float* bias = blockIdx.z ? bv : bk;
    short* C = blockIdx.z ? Cv : Ck;
    gemm_core<false>(A, B, bias, C, KVD, DIM, blockIdx.y * 128, blockIdx.x * 128);
}

// ---------------------------------------------------------------------------
// RoPE in-place on bf16 Q (T,NH,HD) and K (T,NKV,HD); freqs fp32.
// Q is additionally pre-scaled by 1/sqrt(HD) * log2(e): flash_attn's softmax
// then runs in base-2 (exp2 = native v_exp_f32), no per-element scale muls.
// ---------------------------------------------------------------------------
#define QSC (0.08838834764831845f * 1.4426950408889634f)

__global__ __launch_bounds__(256)
void rope_k(short* __restrict__ Q, short* __restrict__ Kc,
            const float* __restrict__ fc, const float* __restrict__ fs) {
    int idx = blockIdx.x * 256 + threadIdx.x;
    const int NQ = T_SEQ * NH  * (HD/2);
    const int NK = T_SEQ * NKV * (HD/2);
    short* base; int t, i; size_t off; float sc;
    if (idx < NQ) {
        i = idx & 63;
        int th = idx >> 6;
        t = th >> 5;
        off = (size_t)th * HD + i*2;
        base = Q; sc = QSC;
    } else if (idx < NQ + NK) {
        int kidx = idx - NQ;
        i = kidx & 63;
        int th = kidx >> 6;
        t = th >> 3;
        off = (size_t)th * HD + i*2;
        base = Kc; sc = 1.0f;
    } else return;
    float re = bf2f(base[off]), im = bf2f(base[off+1]);
    float c = fc[t*64 + i], s = fs[t*64 + i];
    base[off]   = f2bf((re*c - im*s)*sc);
    base[off+1] = f2bf((re*s + im*c)*sc);
}

// ---------------------------------------------------------------------------
// V[T,KVD] -> Vt[KVD,T]  (64x64 LDS tiles)
// ---------------------------------------------------------------------------
__global__ __launch_bounds__(256)
void vtrans(const short* __restrict__ V, short* __restrict__ Vt) {
    __shared__ short sT[64*72];
    const int tid = threadIdx.x;
    const int bt = blockIdx.x, bd = blockIdx.y;
    #pragma unroll
    for (int i = 0; i < 2; i++) {
        int c = i*256 + tid;
        int r = c >> 3, c8 = (c & 7) * 8;
        *(short8*)&sT[r*72 + c8] = *(const short8*)(V + (size_t)(bt*64 + r)*KVD + bd*64 + c8);
    }
    __syncthreads();
    #pragma unroll
    for (int i = 0; i < 2; i++) {
        int c = i*256 + tid;
        int d = c >> 3, t8 = (c & 7) * 8;
        short8 o;
        #pragma unroll
        for (int j = 0; j < 8; j++) o[j] = sT[(t8 + j)*72 + d];
        *(short8*)(Vt + (size_t)(bd*64 + d)*T_SEQ + bt*64 + t8) = o;
    }
}

// ---------------------------------------------------------------------------
// Causal flash attention, kv-grouped: grid (64, 8), block 256 (4 waves).
// Block = (32 q-rows) x (4 heads of one kv group); wave w = head w.
// 2-phase double-buffered K/V staging via global_load_lds (T3-minimum):
// tile kt+1 staged into buf^1 BEFORE computing tile kt; ONE barrier/iter
// whose implicit vmcnt(0) waits on loads issued a full compute phase ago.
// LDS dest is linear (GLD requirement); bank spread via XOR-chunk swizzle
// expressed on the GLOBAL source address (rule #21): slot = chunk ^ (row&7),
// same XOR applied on the LDS read side. Softmax in base-2 (Q pre-scaled by
// scale*log2e in rope_k; exp2 native). DPP reductions; defer-max (T13);
// diagonal-tile-only masking; setprio around MFMA (T5).
// ---------------------------------------------------------------------------
__global__ __launch_bounds__(256, 2)
void flash_attn(const short* __restrict__ Q, const short* __restrict__ Kc,
                const short* __restrict__ Vt, short* __restrict__ O) {
    __shared__ short sK0[64*128];
    __shared__ short sK1[64*128];
    __shared__ short sV0[128*64];     // [d][k]
    __shared__ short sV1[128*64];
    __shared__ short sP[4*2048];      // per-wave 32x64 strip
    const int tid  = threadIdx.x;
    const int wave = tid >> 6, lane = tid & 63;
    const int l15  = lane & 15, lq = lane >> 4;
    const int sw   = l15 & 7;            // read-side XOR key (row&7 == l15&7)
    const int kvg  = blockIdx.y;
    const int qt   = (blockIdx.y < 4) ? (int)blockIdx.x : 63 - (int)blockIdx.x;
    const int hl   = wave;               // head_local 0..3
    const int qb   = qt * 32;

    // Q fragments direct from global: wave's 32 q-rows x 128 d -> 32 VGPRs
    short8 qf[2][4];
    #pragma unroll
    for (int mi = 0; mi < 2; mi++)
        #pragma unroll
        for (int ks = 0; ks < 4; ks++)
            qf[mi][ks] = *(const short8*)(Q + (size_t)(qb + mi*16 + l15)*DIM
                                          + kvg*512 + hl*128 + ks*32 + lq*8);

    short* sPw = sP + wave*2048;

    // staging: K tile = 64 rows x 16 chunks(16B); V tile = 128 rows x 8 chunks.
    // LDS slot (r, jl) holds global chunk jg = jl ^ (r&7).
    int kc_r[4], kc_jg[4], vc_r[4], vc_jg[4];
    #pragma unroll
    for (int i = 0; i < 4; i++) {
        int c = i*256 + tid;
        kc_r[i]  = c >> 4;
        kc_jg[i] = (c & 15) ^ (kc_r[i] & 7);
        vc_r[i]  = c >> 3;
        vc_jg[i] = (c & 7) ^ (vc_r[i] & 7);
    }
    auto stage = [&](short* dK, short* dV, int kt) {
        #pragma unroll
        for (int i = 0; i < 4; i++) {
            int c = i*256 + tid;
            GLD16(Kc + (size_t)(kt*64 + kc_r[i])*KVD + kvg*HD + kc_jg[i]*8,
                  dK + c*8);
            GLD16(Vt + (size_t)(kvg*HD + vc_r[i])*T_SEQ + kt*64 + vc_jg[i]*8,
                  dV + c*8);
        }
    };

    float m_r[2][4], l_r[2][4];
    floatx4 o_acc[2][8];
    #pragma unroll
    for (int mi = 0; mi < 2; mi++) {
        #pragma unroll
        for (int r = 0; r < 4; r++) { m_r[mi][r] = -1e30f; l_r[mi][r] = 0.0f; }
        #pragma unroll
        for (int nd = 0; nd < 8; nd++) o_acc[mi][nd] = (floatx4)(0.0f);
    }

    const int ktmax = qt >> 1;
    stage(sK0, sV0, 0);              // prologue
    __syncthreads();                 // implicit vmcnt(0) drains prologue loads

    for (int kt = 0; kt <= ktmax; kt++) {
        short* bK = (kt & 1) ? sK1 : sK0;
        short* bV = (kt & 1) ? sV1 : sV0;
        // prefetch next tile into the other buffer; in flight across compute
        if (kt < ktmax) stage((kt & 1) ? sK0 : sK1, (kt & 1) ? sV0 : sV1, kt + 1);

        // S = Q K^T: 32q x 64k, K=128 (kf read shared across mi)
        floatx4 s_acc[2][4];
        #pragma unroll
        for (int mi = 0; mi < 2; mi++)
            #pragma unroll
            for (int ni = 0; ni < 4; ni++) s_acc[mi][ni] = (floatx4)(0.0f);
        __builtin_amdgcn_s_setprio(1);
        #pragma unroll
        for (int ks = 0; ks < 4; ks++)
            #pragma unroll
            for (int ni = 0; ni < 4; ni++) {
                short8 kf = *(const short8*)&bK[(ni*16 + l15)*128
                                                + (((ks*4 + lq) ^ sw)*8)];
                s_acc[0][ni] = __builtin_amdgcn_mfma_f32_16x16x32_bf16(qf[0][ks], kf, s_acc[0][ni], 0, 0, 0);
                s_acc[1][ni] = __builtin_amdgcn_mfma_f32_16x16x32_bf16(qf[1][ks], kf, s_acc[1][ni], 0, 0, 0);
            }
        __builtin_amdgcn_s_setprio(0);

        const bool last = (kt == ktmax);

        // mask (diagonal tile only) + online softmax, base-2 domain
        #pragma unroll
        for (int mi = 0; mi < 2; mi++) {
            float sv[4][4], mx[4];
            #pragma unroll
            for (int r = 0; r < 4; r++) mx[r] = -1e30f;
            #pragma unroll
            for (int ni = 0; ni < 4; ni++) {
                int col = kt*64 + ni*16 + l15;
                #pragma unroll
                for (int r = 0; r < 4; r++) {
                    float x = s_acc[mi][ni][r];       // Q pre-scaled: log2 domain
                    if (last) {
                        int row = qb + mi*16 + lq*4 + r;
                        x = (col <= row) ? x : -1e30f;
                    }
                    sv[ni][r] = x;
                    mx[r] = fmaxf(mx[r], x);
                }
            }
            #pragma unroll
            for (int r = 0; r < 4; r++) mx[r] = rowmax16(mx[r]);  // DPP, VALU-only

            // defer-max: only rescale when tile max grew past THR=8 (P <= 2^8)
            float g = fmaxf(fmaxf(mx[0] - m_r[mi][0], mx[1] - m_r[mi][1]),
                            fmaxf(mx[2] - m_r[mi][2], mx[3] - m_r[mi][3]));
            if (__any(g > 8.0f)) {
                #pragma unroll
                for (int r = 0; r < 4; r++) {
                    float mn = fmaxf(m_r[mi][r], mx[r]);
                    float a  = __builtin_amdgcn_exp2f(m_r[mi][r] - mn);
                    m_r[mi][r] = mn;
                    l_r[mi][r] *= a;
                    #pragma unroll
                    for (int nd = 0; nd < 8; nd++) o_acc[mi][nd][r] *= a;
                }
            }

            float rs[4] = {0.0f, 0.0f, 0.0f, 0.0f};
            #pragma unroll
            for (int ni = 0; ni < 4; ni++)
                #pragma unroll
                for (int r = 0; r < 4; r++) {
                    float p = __builtin_amdgcn_exp2f(sv[ni][r] - m_r[mi][r]);
                    sv[ni][r] = p;
                    rs[r] += p;
                }
            #pragma unroll
            for (int r = 0; r < 4; r++) {
                rs[r] = rowsum16(rs[r]);                        // DPP, VALU-only
                l_r[mi][r] += rs[r];
            }

            // P strip -> own-wave LDS (C->A layout), chunk-XOR swizzle
            #pragma unroll
            for (int ni = 0; ni < 4; ni++)
                #pragma unroll
                for (int r = 0; r < 4; r++) {
                    int q = mi*16 + lq*4 + r, k = ni*16 + l15;
                    sPw[q*64 + (((k >> 3) ^ (q & 7))*8) + (k & 7)] = f2bf(sv[ni][r]);
                }
        }
        // no barrier: sP strip is wave-private (lgkmcnt ordering within wave)

        // O += P V (contraction over 64 keys; vf read shared across mi)
        __builtin_amdgcn_s_setprio(1);
        #pragma unroll
        for (int ks = 0; ks < 2; ks++) {
            int kk = ks*32 + lq*8;
            short8 pf[2];
            #pragma unroll
            for (int mi = 0; mi < 2; mi++) {
                int q = mi*16 + l15;
                pf[mi] = *(const short8*)&sPw[q*64 + (((kk >> 3) ^ (q & 7))*8)];
            }
            #pragma unroll
            for (int nd = 0; nd < 8; nd++) {
                short8 vf = *(const short8*)&bV[(nd*16 + l15)*64
                                                + (((ks*4 + lq) ^ sw)*8)];
                o_acc[0][nd] = __builtin_amdgcn_mfma_f32_16x16x32_bf16(pf[0], vf, o_acc[0][nd], 0, 0, 0);
                o_acc[1][nd] = __builtin_amdgcn_mfma_f32_16x16x32_bf16(pf[1], vf, o_acc[1][nd], 0, 0, 0);
            }
        }
        __builtin_amdgcn_s_setprio(0);

        __syncthreads();   // all reads of buf done; drains prefetch vmcnt
    }

    // epilogue
    #pragma unroll
    for (int mi = 0; mi < 2; mi++)
        #pragma unroll
        for (int nd = 0; nd < 8; nd++) {
            int col = (kvg*4 + hl)*HD + nd*16 + l15;
            #pragma unroll
            for (int r = 0; r < 4; r++) {
                int row = qb + mi*16 + lq*4 + r;
                O[(size_t)row*DIM + col] = f2bf(o_acc[mi][nd][r] / l_r[mi][r]);
            }
        }
}

// ---------------------------------------------------------------------------
extern "C" void kernel_launch(void* const* d_in, const int* in_sizes, int n_in,
                              void* d_out, int out_size, void* d_ws, size_t ws_size,
                              hipStream_t stream) {
    const float* x    = (const float*)d_in[0];
    const float* fc   = (const float*)d_in[1];
    const float* fs   = (const float*)d_in[2];
    // d_in[3] mask: causal, analytic. d_in[4,5] caches: dead (pos=0).
    const float* wk_w = (const float*)d_in[6];
    const float* wk_b = (const float*)d_in[7];
    const float* wv_w = (const float*)d_in[8];
    const float* wv_b = (const float*)d_in[9];
    const float* wo_w = (const float*)d_in[10];
    const float* wo_b = (const float*)d_in[11];
    float* out = (float*)d_out;

    short* xb  = (short*)d_ws;                 //  8388608
    short* wkb = xb  + 8388608;                //  4194304
    short* wvb = wkb + 4194304;                //  4194304
    short* wob = wvb + 4194304;                // 16777216
    short* Q   = wob + 16777216;               //  8388608
    short* K   = Q   + 8388608;                //  2097152
    short* V   = K   + 2097152;                //  2097152
    short* Vt  = V   + 2097152;                //  2097152
    short* AO  = Vt  + 2097152;                //  8388608  (total ~113.4 MB)

    cvt_bf16<<<dim3(16384), dim3(256), 0, stream>>>(x, wk_w, wv_w, wo_w, xb, wkb, wvb, wob);

    // reference quirk: q is projected with wo_w/wo_b
    gemm_bt<false><<<dim3(32, 16), dim3(256), 0, stream>>>(xb, wob, wo_b, Q, DIM, DIM);
    gemm_kv<<<dim3(8, 16, 2), dim3(256), 0, stream>>>(xb, wkb, wk_b, K, wvb, wv_b, V);

    int nrope = T_SEQ*NH*(HD/2) + T_SEQ*NKV*(HD/2);
    rope_k<<<dim3((nrope + 255)/256), dim3(256), 0, stream>>>(Q, K, fc, fs);

    vtrans<<<dim3(32, 16), dim3(256), 0, stream>>>(V, Vt);

    flash_attn<<<dim3(64, 8), dim3(256), 0, stream>>>(Q, K, Vt, AO);

    gemm_bt<true><<<dim3(32, 16), dim3(256), 0, stream>>>(AO, wob, wo_b, out, DIM, DIM);
}

// Round 5
// 496.394 us; speedup vs baseline: 1.2003x; 1.0455x over previous
//
#include <hip/hip_runtime.h>
#include <stdint.h>
#include <stddef.h>

#define T_SEQ 2048
#define DIM   4096
#define NH    32
#define NKV   8
#define HD    128
#define KVD   (NKV*HD)   // 1024

typedef __attribute__((ext_vector_type(8))) short short8;
typedef __attribute__((ext_vector_type(4))) float floatx4;
typedef __attribute__((ext_vector_type(2))) unsigned int uintx2;

static __device__ __forceinline__ float bf2f(short u) {
    union { unsigned int i; float f; } c; c.i = ((unsigned int)(unsigned short)u) << 16; return c.f;
}
static __device__ __forceinline__ short f2bf(float f) {
    union { float f; unsigned int u; } c; c.f = f;
    unsigned int r = c.u + 0x7fff + ((c.u >> 16) & 1);
    return (short)(r >> 16);
}
static __device__ __forceinline__ short8 ld8_f2b(const float* p) {
    floatx4 a = *(const floatx4*)p;
    floatx4 b = *(const floatx4*)(p + 4);
    short8 r;
    r[0]=f2bf(a[0]); r[1]=f2bf(a[1]); r[2]=f2bf(a[2]); r[3]=f2bf(a[3]);
    r[4]=f2bf(b[0]); r[5]=f2bf(b[1]); r[6]=f2bf(b[2]); r[7]=f2bf(b[3]);
    return r;
}

// async 16B global->LDS (m97 pattern; LDS dest is wave-uniform-base + lane*16)
#define GLD16(g, l) __builtin_amdgcn_global_load_lds( \
    (const __attribute__((address_space(1))) unsigned int*)(g), \
    (__attribute__((address_space(3))) unsigned int*)(l), 16, 0, 0)

// ---------------------------------------------------------------------------
// fp32 -> bf16 bulk convert: x (8M), wk (4M), wv (4M), wo (16M); 8 elems/thread
// ---------------------------------------------------------------------------
__global__ __launch_bounds__(256)
void cvt_bf16(const float* __restrict__ x, const float* __restrict__ wk,
              const float* __restrict__ wv, const float* __restrict__ wo,
              short* __restrict__ xb, short* __restrict__ wkb,
              short* __restrict__ wvb, short* __restrict__ wob) {
    size_t i8 = ((size_t)blockIdx.x * 256 + threadIdx.x) * 8;
    const float* src; short* dst; size_t off;
    if (i8 < 8388608)        { src = x;  dst = xb;  off = i8; }
    else if (i8 < 12582912)  { src = wk; dst = wkb; off = i8 - 8388608; }
    else if (i8 < 16777216)  { src = wv; dst = wvb; off = i8 - 12582912; }
    else                     { src = wo; dst = wob; off = i8 - 16777216; }
    *(short8*)(dst + off) = ld8_f2b(src + off);
}

// ---------------------------------------------------------------------------
// 2-phase (T3-minimum) GEMM core: C[M,N] = A[M,K]*B[N,K]^T + bias.
// Double-buffered LDS; next-tile global_load_lds issued BEFORE current-tile
// compute, single __syncthreads per K-step. 128x128 tile, BK=32, 4 waves 2x2.
// ---------------------------------------------------------------------------
template<bool C_F32>
static __device__ __forceinline__
void gemm_core(const short* __restrict__ A, const short* __restrict__ B,
               const float* __restrict__ bias, void* __restrict__ Cp,
               int N, int K, int bm, int bn) {
    __shared__ short sA0[128*32];
    __shared__ short sA1[128*32];
    __shared__ short sB0[128*32];
    __shared__ short sB1[128*32];
    const int tid  = threadIdx.x;
    const int wave = tid >> 6, lane = tid & 63;
    const int l15  = lane & 15, lq = lane >> 4;
    const int wm   = (wave >> 1) * 64, wn = (wave & 1) * 64;

    floatx4 acc[4][4];
    #pragma unroll
    for (int i = 0; i < 4; i++)
        #pragma unroll
        for (int j = 0; j < 4; j++)
            acc[i][j] = (floatx4)(0.0f);

    // staging map: chunk c -> lds elem c*8 (lane-linear, 16B/lane)
    const int c0 = tid, c1 = 256 + tid;
    const int r0 = c0 >> 2, k0 = (c0 & 3) * 8;
    const int r1 = c1 >> 2, k1 = (c1 & 3) * 8;
    const short* pA0 = A + (size_t)(bm + r0) * K + k0;
    const short* pA1 = A + (size_t)(bm + r1) * K + k1;
    const short* pB0 = B + (size_t)(bn + r0) * K + k0;
    const short* pB1 = B + (size_t)(bn + r1) * K + k1;

    auto stage = [&](short* dA, short* dB, int kt) {
        GLD16(pA0 + kt, dA + c0 * 8);
        GLD16(pA1 + kt, dA + c1 * 8);
        GLD16(pB0 + kt, dB + c0 * 8);
        GLD16(pB1 + kt, dB + c1 * 8);
    };
    auto compute = [&](const short* dA, const short* dB) {
        short8 af[4], bfr[4];
        #pragma unroll
        for (int mi = 0; mi < 4; mi++)
            af[mi] = *(const short8*)&dA[(wm + mi*16 + l15)*32 + lq*8];
        #pragma unroll
        for (int ni = 0; ni < 4; ni++)
            bfr[ni] = *(const short8*)&dB[(wn + ni*16 + l15)*32 + lq*8];
        #pragma unroll
        for (int mi = 0; mi < 4; mi++)
            #pragma unroll
            for (int ni = 0; ni < 4; ni++)
                acc[mi][ni] = __builtin_amdgcn_mfma_f32_16x16x32_bf16(af[mi], bfr[ni], acc[mi][ni], 0, 0, 0);
    };

    // prologue: fill buf0 with tile 0
    stage(sA0, sB0, 0);
    __syncthreads();                 // implicit vmcnt(0) drains prologue loads

    const int nt = K >> 5;           // K-steps (even: K multiple of 64)
    for (int t = 0; t < nt; t += 2) {
        // step A: prefetch tile t+1 -> buf1, compute tile t from buf0
        stage(sA1, sB1, (t + 1) * 32);
        compute(sA0, sB0);
        __syncthreads();             // vmcnt(0): buf1 loads had full compute to fly
        // step B: prefetch tile t+2 -> buf0, compute tile t+1 from buf1
        if (t + 2 < nt) stage(sA0, sB0, (t + 2) * 32);
        compute(sA1, sB1);
        __syncthreads();
    }

    // epilogue: C/D layout col=lane&15, row=(lane>>4)*4+reg  [m89/m91]
    #pragma unroll
    for (int ni = 0; ni < 4; ni++) {
        int col = bn + wn + ni*16 + l15;
        float bv = bias[col];
        #pragma unroll
        for (int mi = 0; mi < 4; mi++) {
            int row = bm + wm + mi*16 + lq*4;
            #pragma unroll
            for (int r = 0; r < 4; r++) {
                float v = acc[mi][ni][r] + bv;
                if (C_F32) ((float*)Cp)[(size_t)(row + r)*N + col] = v;
                else       ((short*)Cp)[(size_t)(row + r)*N + col] = f2bf(v);
            }
        }
    }
}

template<bool C_F32>
__global__ __launch_bounds__(256)
void gemm_bt(const short* __restrict__ A, const short* __restrict__ B,
             const float* __restrict__ bias, void* __restrict__ Cp,
             int N, int K) {
    gemm_core<C_F32>(A, B, bias, Cp, N, K, blockIdx.y * 128, blockIdx.x * 128);
}

// K and V projections fused into one dispatch (z selects), 256 blocks total
__global__ __launch_bounds__(256)
void gemm_kv(const short* __restrict__ A,
             const short* __restrict__ Bk, const float* __restrict__ bk, short* __restrict__ Ck,
             const short* __restrict__ Bv, const float* __restrict__ bv, short* __restrict__ Cv) {
    const short* B = blockIdx.z ? Bv : Bk;
    const float* bias = blockIdx.z ? bv : bk;
    short* C = blockIdx.z ? Cv : Ck;
    gemm_core<false>(A, B, bias, C, KVD, DIM, blockIdx.y * 128, blockIdx.x * 128);
}

// ---------------------------------------------------------------------------
// RoPE in-place on bf16 Q (T,NH,HD) and K (T,NKV,HD); freqs fp32.
// Q is additionally pre-scaled by 1/sqrt(HD) * log2(e): flash_attn's softmax
// then runs in base-2 (exp2 = native v_exp_f32), no per-element scale muls.
// ---------------------------------------------------------------------------
#define QSC (0.08838834764831845f * 1.4426950408889634f)

__global__ __launch_bounds__(256)
void rope_k(short* __restrict__ Q, short* __restrict__ Kc,
            const float* __restrict__ fc, const float* __restrict__ fs) {
    int idx = blockIdx.x * 256 + threadIdx.x;
    const int NQ = T_SEQ * NH  * (HD/2);
    const int NK = T_SEQ * NKV * (HD/2);
    short* base; int t, i; size_t off; float sc;
    if (idx < NQ) {
        i = idx & 63;
        int th = idx >> 6;
        t = th >> 5;
        off = (size_t)th * HD + i*2;
        base = Q; sc = QSC;
    } else if (idx < NQ + NK) {
        int kidx = idx - NQ;
        i = kidx & 63;
        int th = kidx >> 6;
        t = th >> 3;
        off = (size_t)th * HD + i*2;
        base = Kc; sc = 1.0f;
    } else return;
    float re = bf2f(base[off]), im = bf2f(base[off+1]);
    float c = fc[t*64 + i], s = fs[t*64 + i];
    base[off]   = f2bf((re*c - im*s)*sc);
    base[off+1] = f2bf((re*s + im*c)*sc);
}

// ---------------------------------------------------------------------------
// V[T,KVD] -> Vt[KVD,T]  (64x64 LDS tiles)
// ---------------------------------------------------------------------------
__global__ __launch_bounds__(256)
void vtrans(const short* __restrict__ V, short* __restrict__ Vt) {
    __shared__ short sT[64*72];
    const int tid = threadIdx.x;
    const int bt = blockIdx.x, bd = blockIdx.y;
    #pragma unroll
    for (int i = 0; i < 2; i++) {
        int c = i*256 + tid;
        int r = c >> 3, c8 = (c & 7) * 8;
        *(short8*)&sT[r*72 + c8] = *(const short8*)(V + (size_t)(bt*64 + r)*KVD + bd*64 + c8);
    }
    __syncthreads();
    #pragma unroll
    for (int i = 0; i < 2; i++) {
        int c = i*256 + tid;
        int d = c >> 3, t8 = (c & 7) * 8;
        short8 o;
        #pragma unroll
        for (int j = 0; j < 8; j++) o[j] = sT[(t8 + j)*72 + d];
        *(short8*)(Vt + (size_t)(bd*64 + d)*T_SEQ + bt*64 + t8) = o;
    }
}

// ---------------------------------------------------------------------------
// Causal flash attention, kv-grouped: grid (64, 8), block 256 (4 waves).
// Block = (32 q-rows) x (4 heads of one kv group); wave w = head w.
// 2-phase double-buffered K/V staging via global_load_lds; XOR-chunk swizzle
// on the global source (rule #21), same XOR on read side.
// SWAPPED QK^T (T12-enabler): S^T = mfma(K_frag, Q_frag) -> each lane holds
// 16 S-values for ONE q-row (q = l15). Softmax row-reduce = 15 in-lane ops +
// shfl_xor(16/32); stats are 1 scalar per mi; P packed via v_cvt_pk_bf16_f32
// and written as 8x ds_write_b64 (k-contiguous). Rescale/epilogue transpose
// stats->acc layout via shfl (rare / once). Base-2 softmax (Q pre-scaled).
// Defer-max (T13); diagonal-tile-only masking; setprio around MFMA (T5).
// ---------------------------------------------------------------------------
__global__ __launch_bounds__(256, 2)
void flash_attn(const short* __restrict__ Q, const short* __restrict__ Kc,
                const short* __restrict__ Vt, short* __restrict__ O) {
    __shared__ short sK0[64*128];
    __shared__ short sK1[64*128];
    __shared__ short sV0[128*64];     // [d][k]
    __shared__ short sV1[128*64];
    __shared__ short sP[4*2048];      // per-wave 32q x 64k strip (128 B rows)
    const int tid  = threadIdx.x;
    const int wave = tid >> 6, lane = tid & 63;
    const int l15  = lane & 15, lq = lane >> 4;
    const int sw   = l15 & 7;            // row-keyed XOR (row&7 == l15&7 here)
    const int kvg  = blockIdx.y;
    const int qt   = (blockIdx.y < 4) ? (int)blockIdx.x : 63 - (int)blockIdx.x;
    const int hl   = wave;               // head_local 0..3
    const int qb   = qt * 32;

    // Q fragments direct from global: wave's 32 q-rows x 128 d -> 32 VGPRs.
    // Layout doubles as MFMA B-operand (rows q=l15, elems d=lq*8) for swapped QK^T.
    short8 qf[2][4];
    #pragma unroll
    for (int mi = 0; mi < 2; mi++)
        #pragma unroll
        for (int ks = 0; ks < 4; ks++)
            qf[mi][ks] = *(const short8*)(Q + (size_t)(qb + mi*16 + l15)*DIM
                                          + kvg*512 + hl*128 + ks*32 + lq*8);

    char* pw = (char*)(sP + wave*2048);   // wave-private 4 KB

    // staging: K tile = 64 rows x 16 chunks(16B); V tile = 128 rows x 8 chunks.
    // LDS slot (r, jl) holds global chunk jg = jl ^ (r&7).
    int kc_r[4], kc_jg[4], vc_r[4], vc_jg[4];
    #pragma unroll
    for (int i = 0; i < 4; i++) {
        int c = i*256 + tid;
        kc_r[i]  = c >> 4;
        kc_jg[i] = (c & 15) ^ (kc_r[i] & 7);
        vc_r[i]  = c >> 3;
        vc_jg[i] = (c & 7) ^ (vc_r[i] & 7);
    }
    auto stage = [&](short* dK, short* dV, int kt) {
        #pragma unroll
        for (int i = 0; i < 4; i++) {
            int c = i*256 + tid;
            GLD16(Kc + (size_t)(kt*64 + kc_r[i])*KVD + kvg*HD + kc_jg[i]*8,
                  dK + c*8);
            GLD16(Vt + (size_t)(kvg*HD + vc_r[i])*T_SEQ + kt*64 + vc_jg[i]*8,
                  dV + c*8);
        }
    };

    float m_r[2] = {-1e30f, -1e30f};     // stats layout: lane holds q = mi*16+l15
    float l_r[2] = {0.0f, 0.0f};
    floatx4 o_acc[2][8];                 // acc layout: rows q = lq*4+r, col d = l15
    #pragma unroll
    for (int mi = 0; mi < 2; mi++)
        #pragma unroll
        for (int nd = 0; nd < 8; nd++) o_acc[mi][nd] = (floatx4)(0.0f);

    const int ktmax = qt >> 1;
    stage(sK0, sV0, 0);              // prologue
    __syncthreads();                 // implicit vmcnt(0) drains prologue loads

    for (int kt = 0; kt <= ktmax; kt++) {
        short* bK = (kt & 1) ? sK1 : sK0;
        short* bV = (kt & 1) ? sV1 : sV0;
        // prefetch next tile into the other buffer; in flight across compute
        if (kt < ktmax) stage((kt & 1) ? sK0 : sK1, (kt & 1) ? sV0 : sV1, kt + 1);

        // S^T = K Q^T: D[k][q]; per (mi,ni): rows k=lq*4+r, col q=l15
        floatx4 s_acc[2][4];
        #pragma unroll
        for (int mi = 0; mi < 2; mi++)
            #pragma unroll
            for (int ni = 0; ni < 4; ni++) s_acc[mi][ni] = (floatx4)(0.0f);
        __builtin_amdgcn_s_setprio(1);
        #pragma unroll
        for (int ks = 0; ks < 4; ks++)
            #pragma unroll
            for (int ni = 0; ni < 4; ni++) {
                short8 kf = *(const short8*)&bK[(ni*16 + l15)*128
                                                + (((ks*4 + lq) ^ sw)*8)];
                s_acc[0][ni] = __builtin_amdgcn_mfma_f32_16x16x32_bf16(kf, qf[0][ks], s_acc[0][ni], 0, 0, 0);
                s_acc[1][ni] = __builtin_amdgcn_mfma_f32_16x16x32_bf16(kf, qf[1][ks], s_acc[1][ni], 0, 0, 0);
            }
        __builtin_amdgcn_s_setprio(0);

        const bool last = (kt == ktmax);

        // online softmax, base-2; lane owns one q-row per mi
        #pragma unroll
        for (int mi = 0; mi < 2; mi++) {
            float sv[4][4];
            float mx = -1e30f;
            const int qrow = qb + mi*16 + l15;
            #pragma unroll
            for (int ni = 0; ni < 4; ni++)
                #pragma unroll
                for (int r = 0; r < 4; r++) {
                    float x = s_acc[mi][ni][r];
                    if (last) {
                        int kcol = kt*64 + ni*16 + lq*4 + r;
                        x = (kcol <= qrow) ? x : -1e30f;
                    }
                    sv[ni][r] = x;
                    mx = fmaxf(mx, x);
                }
            mx = fmaxf(mx, __shfl_xor(mx, 16));
            mx = fmaxf(mx, __shfl_xor(mx, 32));

            // defer-max: only rescale when row max grew past THR=8 (P <= 2^8)
            if (__any(mx - m_r[mi] > 8.0f)) {
                float mn = fmaxf(m_r[mi], mx);
                float a  = __builtin_amdgcn_exp2f(m_r[mi] - mn);
                m_r[mi] = mn;
                l_r[mi] *= a;
                float ar[4];
                #pragma unroll
                for (int r = 0; r < 4; r++) ar[r] = __shfl(a, lq*4 + r);
                #pragma unroll
                for (int nd = 0; nd < 8; nd++)
                    #pragma unroll
                    for (int r = 0; r < 4; r++) o_acc[mi][nd][r] *= ar[r];
            }

            float rs = 0.0f;
            #pragma unroll
            for (int ni = 0; ni < 4; ni++)
                #pragma unroll
                for (int r = 0; r < 4; r++) {
                    float p = __builtin_amdgcn_exp2f(sv[ni][r] - m_r[mi]);
                    sv[ni][r] = p;
                    rs += p;
                }
            rs += __shfl_xor(rs, 16);
            rs += __shfl_xor(rs, 32);
            l_r[mi] += rs;

            // pack P (4 k-consecutive bf16 per ni) -> ds_write_b64, XOR-swizzled
            char* rowp = pw + (mi*16 + l15)*128 + (lq & 1)*8;
            #pragma unroll
            for (int ni = 0; ni < 4; ni++) {
                unsigned int lo, hi;
                asm("v_cvt_pk_bf16_f32 %0, %1, %2" : "=v"(lo) : "v"(sv[ni][0]), "v"(sv[ni][1]));
                asm("v_cvt_pk_bf16_f32 %0, %1, %2" : "=v"(hi) : "v"(sv[ni][2]), "v"(sv[ni][3]));
                int kc = ni*2 + (lq >> 1);
                *(uintx2*)(rowp + ((kc ^ sw) * 16)) = (uintx2){lo, hi};
            }
        }
        // no barrier: sP strip is wave-private (lgkmcnt ordering within wave)

        // O += P V (contraction over 64 keys; vf read shared across mi)
        __builtin_amdgcn_s_setprio(1);
        #pragma unroll
        for (int ks = 0; ks < 2; ks++) {
            short8 pf[2];
            #pragma unroll
            for (int mi = 0; mi < 2; mi++)
                pf[mi] = *(const short8*)(pw + (mi*16 + l15)*128
                                          + (((ks*4 + lq) ^ sw)*16));
            #pragma unroll
            for (int nd = 0; nd < 8; nd++) {
                short8 vf = *(const short8*)&bV[(nd*16 + l15)*64
                                                + (((ks*4 + lq) ^ sw)*8)];
                o_acc[0][nd] = __builtin_amdgcn_mfma_f32_16x16x32_bf16(pf[0], vf, o_acc[0][nd], 0, 0, 0);
                o_acc[1][nd] = __builtin_amdgcn_mfma_f32_16x16x32_bf16(pf[1], vf, o_acc[1][nd], 0, 0, 0);
            }
        }
        __builtin_amdgcn_s_setprio(0);

        __syncthreads();   // all reads of buf done; drains prefetch vmcnt
    }

    // epilogue: transpose 1/l from stats layout (q=l15) to acc layout (q=lq*4+r)
    float rec[2][4];
    #pragma unroll
    for (int mi = 0; mi < 2; mi++) {
        float rv = 1.0f / l_r[mi];
        #pragma unroll
        for (int r = 0; r < 4; r++) rec[mi][r] = __shfl(rv, lq*4 + r);
    }
    #pragma unroll
    for (int mi = 0; mi < 2; mi++)
        #pragma unroll
        for (int nd = 0; nd < 8; nd++) {
            int col = (kvg*4 + hl)*HD + nd*16 + l15;
            #pragma unroll
            for (int r = 0; r < 4; r++) {
                int row = qb + mi*16 + lq*4 + r;
                O[(size_t)row*DIM + col] = f2bf(o_acc[mi][nd][r] * rec[mi][r]);
            }
        }
}

// ---------------------------------------------------------------------------
extern "C" void kernel_launch(void* const* d_in, const int* in_sizes, int n_in,
                              void* d_out, int out_size, void* d_ws, size_t ws_size,
                              hipStream_t stream) {
    const float* x    = (const float*)d_in[0];
    const float* fc   = (const float*)d_in[1];
    const float* fs   = (const float*)d_in[2];
    // d_in[3] mask: causal, analytic. d_in[4,5] caches: dead (pos=0).
    const float* wk_w = (const float*)d_in[6];
    const float* wk_b = (const float*)d_in[7];
    const float* wv_w = (const float*)d_in[8];
    const float* wv_b = (const float*)d_in[9];
    const float* wo_w = (const float*)d_in[10];
    const float* wo_b = (const float*)d_in[11];
    float* out = (float*)d_out;

    short* xb  = (short*)d_ws;                 //  8388608
    short* wkb = xb  + 8388608;                //  4194304
    short* wvb = wkb + 4194304;                //  4194304
    short* wob = wvb + 4194304;                // 16777216
    short* Q   = wob + 16777216;               //  8388608
    short* K   = Q   + 8388608;                //  2097152
    short* V   = K   + 2097152;                //  2097152
    short* Vt  = V   + 2097152;                //  2097152
    short* AO  = Vt  + 2097152;                //  8388608  (total ~113.4 MB)

    cvt_bf16<<<dim3(16384), dim3(256), 0, stream>>>(x, wk_w, wv_w, wo_w, xb, wkb, wvb, wob);

    // reference quirk: q is projected with wo_w/wo_b
    gemm_bt<false><<<dim3(32, 16), dim3(256), 0, stream>>>(xb, wob, wo_b, Q, DIM, DIM);
    gemm_kv<<<dim3(8, 16, 2), dim3(256), 0, stream>>>(xb, wkb, wk_b, K, wvb, wv_b, V);

    int nrope = T_SEQ*NH*(HD/2) + T_SEQ*NKV*(HD/2);
    rope_k<<<dim3((nrope + 255)/256), dim3(256), 0, stream>>>(Q, K, fc, fs);

    vtrans<<<dim3(32, 16), dim3(256), 0, stream>>>(V, Vt);

    flash_attn<<<dim3(64, 8), dim3(256), 0, stream>>>(Q, K, Vt, AO);

    gemm_bt<true><<<dim3(32, 16), dim3(256), 0, stream>>>(AO, wob, wo_b, out, DIM, DIM);
}

// Round 6
// 487.313 us; speedup vs baseline: 1.2226x; 1.0186x over previous
//
#include <hip/hip_runtime.h>
#include <stdint.h>
#include <stddef.h>

#define T_SEQ 2048
#define DIM   4096
#define NH    32
#define NKV   8
#define HD    128
#define KVD   (NKV*HD)   // 1024

typedef __attribute__((ext_vector_type(8))) short short8;
typedef __attribute__((ext_vector_type(4))) float floatx4;
typedef __attribute__((ext_vector_type(2))) unsigned int uintx2;

static __device__ __forceinline__ float bf2f(short u) {
    union { unsigned int i; float f; } c; c.i = ((unsigned int)(unsigned short)u) << 16; return c.f;
}
static __device__ __forceinline__ short f2bf(float f) {
    union { float f; unsigned int u; } c; c.f = f;
    unsigned int r = c.u + 0x7fff + ((c.u >> 16) & 1);
    return (short)(r >> 16);
}
static __device__ __forceinline__ short8 ld8_f2b(const float* p) {
    floatx4 a = *(const floatx4*)p;
    floatx4 b = *(const floatx4*)(p + 4);
    short8 r;
    r[0]=f2bf(a[0]); r[1]=f2bf(a[1]); r[2]=f2bf(a[2]); r[3]=f2bf(a[3]);
    r[4]=f2bf(b[0]); r[5]=f2bf(b[1]); r[6]=f2bf(b[2]); r[7]=f2bf(b[3]);
    return r;
}

// async 16B global->LDS (m97 pattern; LDS dest is wave-uniform-base + lane*16)
#define GLD16(g, l) __builtin_amdgcn_global_load_lds( \
    (const __attribute__((address_space(1))) unsigned int*)(g), \
    (__attribute__((address_space(3))) unsigned int*)(l), 16, 0, 0)

// ---------------------------------------------------------------------------
// fp32 -> bf16 bulk convert: x (8M), wk (4M), wv (4M), wo (16M); 8 elems/thread
// ---------------------------------------------------------------------------
__global__ __launch_bounds__(256)
void cvt_bf16(const float* __restrict__ x, const float* __restrict__ wk,
              const float* __restrict__ wv, const float* __restrict__ wo,
              short* __restrict__ xb, short* __restrict__ wkb,
              short* __restrict__ wvb, short* __restrict__ wob) {
    size_t i8 = ((size_t)blockIdx.x * 256 + threadIdx.x) * 8;
    const float* src; short* dst; size_t off;
    if (i8 < 8388608)        { src = x;  dst = xb;  off = i8; }
    else if (i8 < 12582912)  { src = wk; dst = wkb; off = i8 - 8388608; }
    else if (i8 < 16777216)  { src = wv; dst = wvb; off = i8 - 12582912; }
    else                     { src = wo; dst = wob; off = i8 - 16777216; }
    *(short8*)(dst + off) = ld8_f2b(src + off);
}

// ---------------------------------------------------------------------------
// Counted-vmcnt (T3+T4) GEMM core: C[M,N] = A[M,K]*B[N,K]^T + bias.
// 3 LDS buffers (48 KB), prefetch 2 tiles ahead via global_load_lds.
// Main loop: s_waitcnt vmcnt(4) (tile t's 4 loads done; t+1's 4 stay in
// flight) + RAW s_barrier — never drains the pipeline. Stage t+2 after the
// barrier (all waves past their t-1 reads). Final iter peels with vmcnt(0).
// 128x128 tile, BK=32, 4 waves 2x2.
// ---------------------------------------------------------------------------
template<bool C_F32>
static __device__ __forceinline__
void gemm_core(const short* __restrict__ A, const short* __restrict__ B,
               const float* __restrict__ bias, void* __restrict__ Cp,
               int N, int K, int bm, int bn) {
    __shared__ short sA0[128*32];
    __shared__ short sA1[128*32];
    __shared__ short sA2[128*32];
    __shared__ short sB0[128*32];
    __shared__ short sB1[128*32];
    __shared__ short sB2[128*32];
    const int tid  = threadIdx.x;
    const int wave = tid >> 6, lane = tid & 63;
    const int l15  = lane & 15, lq = lane >> 4;
    const int wm   = (wave >> 1) * 64, wn = (wave & 1) * 64;

    floatx4 acc[4][4];
    #pragma unroll
    for (int i = 0; i < 4; i++)
        #pragma unroll
        for (int j = 0; j < 4; j++)
            acc[i][j] = (floatx4)(0.0f);

    // staging map: chunk c -> lds elem c*8 (lane-linear, 16B/lane)
    const int c0 = tid, c1 = 256 + tid;
    const int r0 = c0 >> 2, k0 = (c0 & 3) * 8;
    const int r1 = c1 >> 2, k1 = (c1 & 3) * 8;
    const short* pA0 = A + (size_t)(bm + r0) * K + k0;
    const short* pA1 = A + (size_t)(bm + r1) * K + k1;
    const short* pB0 = B + (size_t)(bn + r0) * K + k0;
    const short* pB1 = B + (size_t)(bn + r1) * K + k1;

    auto stage = [&](short* dA, short* dB, int kt) {
        GLD16(pA0 + kt, dA + c0 * 8);
        GLD16(pA1 + kt, dA + c1 * 8);
        GLD16(pB0 + kt, dB + c0 * 8);
        GLD16(pB1 + kt, dB + c1 * 8);
    };
    auto compute = [&](const short* dA, const short* dB) {
        short8 af[4], bfr[4];
        #pragma unroll
        for (int mi = 0; mi < 4; mi++)
            af[mi] = *(const short8*)&dA[(wm + mi*16 + l15)*32 + lq*8];
        #pragma unroll
        for (int ni = 0; ni < 4; ni++)
            bfr[ni] = *(const short8*)&dB[(wn + ni*16 + l15)*32 + lq*8];
        #pragma unroll
        for (int mi = 0; mi < 4; mi++)
            #pragma unroll
            for (int ni = 0; ni < 4; ni++)
                acc[mi][ni] = __builtin_amdgcn_mfma_f32_16x16x32_bf16(af[mi], bfr[ni], acc[mi][ni], 0, 0, 0);
    };

    // prologue: tiles 0 and 1 in flight (8 loads/wave outstanding)
    stage(sA0, sB0, 0);
    stage(sA1, sB1, 32);
    short *cA = sA0, *cB = sB0;   // holds tile t
    short *nA = sA1, *nB = sB1;   // holds tile t+1 (in flight)
    short *fA = sA2, *fB = sB2;   // free; staged with tile t+2

    const int nt = K >> 5;        // K=4096 -> 128 steps
    for (int t = 0; t < nt - 1; ++t) {
        asm volatile("s_waitcnt vmcnt(4)" ::: "memory");  // tile t landed; t+1 in flight
        __builtin_amdgcn_s_barrier();
        if (t + 2 < nt) stage(fA, fB, (t + 2) * 32);
        compute(cA, cB);
        short* x;
        x = cA; cA = nA; nA = fA; fA = x;
        x = cB; cB = nB; nB = fB; fB = x;
    }
    asm volatile("s_waitcnt vmcnt(0)" ::: "memory");      // last tile landed
    __builtin_amdgcn_s_barrier();
    compute(cA, cB);

    // epilogue: C/D layout col=lane&15, row=(lane>>4)*4+reg  [m89/m91]
    #pragma unroll
    for (int ni = 0; ni < 4; ni++) {
        int col = bn + wn + ni*16 + l15;
        float bv = bias[col];
        #pragma unroll
        for (int mi = 0; mi < 4; mi++) {
            int row = bm + wm + mi*16 + lq*4;
            #pragma unroll
            for (int r = 0; r < 4; r++) {
                float v = acc[mi][ni][r] + bv;
                if (C_F32) ((float*)Cp)[(size_t)(row + r)*N + col] = v;
                else       ((short*)Cp)[(size_t)(row + r)*N + col] = f2bf(v);
            }
        }
    }
}

template<bool C_F32>
__global__ __launch_bounds__(256)
void gemm_bt(const short* __restrict__ A, const short* __restrict__ B,
             const float* __restrict__ bias, void* __restrict__ Cp,
             int N, int K) {
    gemm_core<C_F32>(A, B, bias, Cp, N, K, blockIdx.y * 128, blockIdx.x * 128);
}

// Fused Q/K/V projections, one dispatch: grid (48, 16) = 768 blocks = 3/CU
// at 48 KB LDS. ct<32 -> Q (wob), ct<40 -> K (wkb), else V (wvb); same A.
// (Round-2 fusion was time-neutral under the drain-stall structure; with
// counted-vmcnt the extra co-residency buys real latency overlap for the
// kv tiles that otherwise run at 1 block/CU.)
__global__ __launch_bounds__(256)
void gemm_qkv(const short* __restrict__ A,
              const short* __restrict__ Bq, const float* __restrict__ bq, short* __restrict__ Cq,
              const short* __restrict__ Bk, const float* __restrict__ bk, short* __restrict__ Ck,
              const short* __restrict__ Bv, const float* __restrict__ bv, short* __restrict__ Cv) {
    const int ct = blockIdx.x;
    const short* B; const float* bias; short* C; int N, bn;
    if (ct < 32)      { B = Bq; bias = bq; C = Cq; N = DIM; bn = ct*128; }
    else if (ct < 40) { B = Bk; bias = bk; C = Ck; N = KVD; bn = (ct-32)*128; }
    else              { B = Bv; bias = bv; C = Cv; N = KVD; bn = (ct-40)*128; }
    gemm_core<false>(A, B, bias, C, N, DIM, blockIdx.y * 128, bn);
}

// ---------------------------------------------------------------------------
// RoPE in-place on bf16 Q (T,NH,HD) and K (T,NKV,HD); freqs fp32.
// Q is additionally pre-scaled by 1/sqrt(HD) * log2(e): flash_attn's softmax
// then runs in base-2 (exp2 = native v_exp_f32), no per-element scale muls.
// ---------------------------------------------------------------------------
#define QSC (0.08838834764831845f * 1.4426950408889634f)

__global__ __launch_bounds__(256)
void rope_k(short* __restrict__ Q, short* __restrict__ Kc,
            const float* __restrict__ fc, const float* __restrict__ fs) {
    int idx = blockIdx.x * 256 + threadIdx.x;
    const int NQ = T_SEQ * NH  * (HD/2);
    const int NK = T_SEQ * NKV * (HD/2);
    short* base; int t, i; size_t off; float sc;
    if (idx < NQ) {
        i = idx & 63;
        int th = idx >> 6;
        t = th >> 5;
        off = (size_t)th * HD + i*2;
        base = Q; sc = QSC;
    } else if (idx < NQ + NK) {
        int kidx = idx - NQ;
        i = kidx & 63;
        int th = kidx >> 6;
        t = th >> 3;
        off = (size_t)th * HD + i*2;
        base = Kc; sc = 1.0f;
    } else return;
    float re = bf2f(base[off]), im = bf2f(base[off+1]);
    float c = fc[t*64 + i], s = fs[t*64 + i];
    base[off]   = f2bf((re*c - im*s)*sc);
    base[off+1] = f2bf((re*s + im*c)*sc);
}

// ---------------------------------------------------------------------------
// V[T,KVD] -> Vt[KVD,T]  (64x64 LDS tiles)
// ---------------------------------------------------------------------------
__global__ __launch_bounds__(256)
void vtrans(const short* __restrict__ V, short* __restrict__ Vt) {
    __shared__ short sT[64*72];
    const int tid = threadIdx.x;
    const int bt = blockIdx.x, bd = blockIdx.y;
    #pragma unroll
    for (int i = 0; i < 2; i++) {
        int c = i*256 + tid;
        int r = c >> 3, c8 = (c & 7) * 8;
        *(short8*)&sT[r*72 + c8] = *(const short8*)(V + (size_t)(bt*64 + r)*KVD + bd*64 + c8);
    }
    __syncthreads();
    #pragma unroll
    for (int i = 0; i < 2; i++) {
        int c = i*256 + tid;
        int d = c >> 3, t8 = (c & 7) * 8;
        short8 o;
        #pragma unroll
        for (int j = 0; j < 8; j++) o[j] = sT[(t8 + j)*72 + d];
        *(short8*)(Vt + (size_t)(bd*64 + d)*T_SEQ + bt*64 + t8) = o;
    }
}

// ---------------------------------------------------------------------------
// Causal flash attention, kv-grouped: grid (64, 8), block 256 (4 waves).
// Block = (32 q-rows) x (4 heads of one kv group); wave w = head w.
// 2-phase double-buffered K/V staging via global_load_lds; XOR-chunk swizzle
// on the global source (rule #21), same XOR on read side.
// SWAPPED QK^T (T12-enabler): S^T = mfma(K_frag, Q_frag) -> each lane holds
// 16 S-values for ONE q-row (q = l15). Softmax row-reduce = 15 in-lane ops +
// shfl_xor(16/32); stats are 1 scalar per mi; P packed via v_cvt_pk_bf16_f32
// and written as 8x ds_write_b64 (k-contiguous). Rescale/epilogue transpose
// stats->acc layout via shfl (rare / once). Base-2 softmax (Q pre-scaled).
// Defer-max (T13); diagonal-tile-only masking; setprio around MFMA (T5).
// ---------------------------------------------------------------------------
__global__ __launch_bounds__(256, 2)
void flash_attn(const short* __restrict__ Q, const short* __restrict__ Kc,
                const short* __restrict__ Vt, short* __restrict__ O) {
    __shared__ short sK0[64*128];
    __shared__ short sK1[64*128];
    __shared__ short sV0[128*64];     // [d][k]
    __shared__ short sV1[128*64];
    __shared__ short sP[4*2048];      // per-wave 32q x 64k strip (128 B rows)
    const int tid  = threadIdx.x;
    const int wave = tid >> 6, lane = tid & 63;
    const int l15  = lane & 15, lq = lane >> 4;
    const int sw   = l15 & 7;            // row-keyed XOR (row&7 == l15&7 here)
    const int kvg  = blockIdx.y;
    const int qt   = (blockIdx.y < 4) ? (int)blockIdx.x : 63 - (int)blockIdx.x;
    const int hl   = wave;               // head_local 0..3
    const int qb   = qt * 32;

    // Q fragments direct from global: wave's 32 q-rows x 128 d -> 32 VGPRs.
    // Layout doubles as MFMA B-operand (rows q=l15, elems d=lq*8) for swapped QK^T.
    short8 qf[2][4];
    #pragma unroll
    for (int mi = 0; mi < 2; mi++)
        #pragma unroll
        for (int ks = 0; ks < 4; ks++)
            qf[mi][ks] = *(const short8*)(Q + (size_t)(qb + mi*16 + l15)*DIM
                                          + kvg*512 + hl*128 + ks*32 + lq*8);

    char* pw = (char*)(sP + wave*2048);   // wave-private 4 KB

    // staging: K tile = 64 rows x 16 chunks(16B); V tile = 128 rows x 8 chunks.
    // LDS slot (r, jl) holds global chunk jg = jl ^ (r&7).
    int kc_r[4], kc_jg[4], vc_r[4], vc_jg[4];
    #pragma unroll
    for (int i = 0; i < 4; i++) {
        int c = i*256 + tid;
        kc_r[i]  = c >> 4;
        kc_jg[i] = (c & 15) ^ (kc_r[i] & 7);
        vc_r[i]  = c >> 3;
        vc_jg[i] = (c & 7) ^ (vc_r[i] & 7);
    }
    auto stage = [&](short* dK, short* dV, int kt) {
        #pragma unroll
        for (int i = 0; i < 4; i++) {
            int c = i*256 + tid;
            GLD16(Kc + (size_t)(kt*64 + kc_r[i])*KVD + kvg*HD + kc_jg[i]*8,
                  dK + c*8);
            GLD16(Vt + (size_t)(kvg*HD + vc_r[i])*T_SEQ + kt*64 + vc_jg[i]*8,
                  dV + c*8);
        }
    };

    float m_r[2] = {-1e30f, -1e30f};     // stats layout: lane holds q = mi*16+l15
    float l_r[2] = {0.0f, 0.0f};
    floatx4 o_acc[2][8];                 // acc layout: rows q = lq*4+r, col d = l15
    #pragma unroll
    for (int mi = 0; mi < 2; mi++)
        #pragma unroll
        for (int nd = 0; nd < 8; nd++) o_acc[mi][nd] = (floatx4)(0.0f);

    const int ktmax = qt >> 1;
    stage(sK0, sV0, 0);              // prologue
    __syncthreads();                 // implicit vmcnt(0) drains prologue loads

    for (int kt = 0; kt <= ktmax; kt++) {
        short* bK = (kt & 1) ? sK1 : sK0;
        short* bV = (kt & 1) ? sV1 : sV0;
        // prefetch next tile into the other buffer; in flight across compute
        if (kt < ktmax) stage((kt & 1) ? sK0 : sK1, (kt & 1) ? sV0 : sV1, kt + 1);

        // S^T = K Q^T: D[k][q]; per (mi,ni): rows k=lq*4+r, col q=l15
        floatx4 s_acc[2][4];
        #pragma unroll
        for (int mi = 0; mi < 2; mi++)
            #pragma unroll
            for (int ni = 0; ni < 4; ni++) s_acc[mi][ni] = (floatx4)(0.0f);
        __builtin_amdgcn_s_setprio(1);
        #pragma unroll
        for (int ks = 0; ks < 4; ks++)
            #pragma unroll
            for (int ni = 0; ni < 4; ni++) {
                short8 kf = *(const short8*)&bK[(ni*16 + l15)*128
                                                + (((ks*4 + lq) ^ sw)*8)];
                s_acc[0][ni] = __builtin_amdgcn_mfma_f32_16x16x32_bf16(kf, qf[0][ks], s_acc[0][ni], 0, 0, 0);
                s_acc[1][ni] = __builtin_amdgcn_mfma_f32_16x16x32_bf16(kf, qf[1][ks], s_acc[1][ni], 0, 0, 0);
            }
        __builtin_amdgcn_s_setprio(0);

        const bool last = (kt == ktmax);

        // online softmax, base-2; lane owns one q-row per mi
        #pragma unroll
        for (int mi = 0; mi < 2; mi++) {
            float sv[4][4];
            float mx = -1e30f;
            const int qrow = qb + mi*16 + l15;
            #pragma unroll
            for (int ni = 0; ni < 4; ni++)
                #pragma unroll
                for (int r = 0; r < 4; r++) {
                    float x = s_acc[mi][ni][r];
                    if (last) {
                        int kcol = kt*64 + ni*16 + lq*4 + r;
                        x = (kcol <= qrow) ? x : -1e30f;
                    }
                    sv[ni][r] = x;
                    mx = fmaxf(mx, x);
                }
            mx = fmaxf(mx, __shfl_xor(mx, 16));
            mx = fmaxf(mx, __shfl_xor(mx, 32));

            // defer-max: only rescale when row max grew past THR=8 (P <= 2^8)
            if (__any(mx - m_r[mi] > 8.0f)) {
                float mn = fmaxf(m_r[mi], mx);
                float a  = __builtin_amdgcn_exp2f(m_r[mi] - mn);
                m_r[mi] = mn;
                l_r[mi] *= a;
                float ar[4];
                #pragma unroll
                for (int r = 0; r < 4; r++) ar[r] = __shfl(a, lq*4 + r);
                #pragma unroll
                for (int nd = 0; nd < 8; nd++)
                    #pragma unroll
                    for (int r = 0; r < 4; r++) o_acc[mi][nd][r] *= ar[r];
            }

            float rs = 0.0f;
            #pragma unroll
            for (int ni = 0; ni < 4; ni++)
                #pragma unroll
                for (int r = 0; r < 4; r++) {
                    float p = __builtin_amdgcn_exp2f(sv[ni][r] - m_r[mi]);
                    sv[ni][r] = p;
                    rs += p;
                }
            rs += __shfl_xor(rs, 16);
            rs += __shfl_xor(rs, 32);
            l_r[mi] += rs;

            // pack P (4 k-consecutive bf16 per ni) -> ds_write_b64, XOR-swizzled
            char* rowp = pw + (mi*16 + l15)*128 + (lq & 1)*8;
            #pragma unroll
            for (int ni = 0; ni < 4; ni++) {
                unsigned int lo, hi;
                asm("v_cvt_pk_bf16_f32 %0, %1, %2" : "=v"(lo) : "v"(sv[ni][0]), "v"(sv[ni][1]));
                asm("v_cvt_pk_bf16_f32 %0, %1, %2" : "=v"(hi) : "v"(sv[ni][2]), "v"(sv[ni][3]));
                int kc = ni*2 + (lq >> 1);
                *(uintx2*)(rowp + ((kc ^ sw) * 16)) = (uintx2){lo, hi};
            }
        }
        // no barrier: sP strip is wave-private (lgkmcnt ordering within wave)

        // O += P V (contraction over 64 keys; vf read shared across mi)
        __builtin_amdgcn_s_setprio(1);
        #pragma unroll
        for (int ks = 0; ks < 2; ks++) {
            short8 pf[2];
            #pragma unroll
            for (int mi = 0; mi < 2; mi++)
                pf[mi] = *(const short8*)(pw + (mi*16 + l15)*128
                                          + (((ks*4 + lq) ^ sw)*16));
            #pragma unroll
            for (int nd = 0; nd < 8; nd++) {
                short8 vf = *(const short8*)&bV[(nd*16 + l15)*64
                                                + (((ks*4 + lq) ^ sw)*8)];
                o_acc[0][nd] = __builtin_amdgcn_mfma_f32_16x16x32_bf16(pf[0], vf, o_acc[0][nd], 0, 0, 0);
                o_acc[1][nd] = __builtin_amdgcn_mfma_f32_16x16x32_bf16(pf[1], vf, o_acc[1][nd], 0, 0, 0);
            }
        }
        __builtin_amdgcn_s_setprio(0);

        __syncthreads();   // all reads of buf done; drains prefetch vmcnt
    }

    // epilogue: transpose 1/l from stats layout (q=l15) to acc layout (q=lq*4+r)
    float rec[2][4];
    #pragma unroll
    for (int mi = 0; mi < 2; mi++) {
        float rv = 1.0f / l_r[mi];
        #pragma unroll
        for (int r = 0; r < 4; r++) rec[mi][r] = __shfl(rv, lq*4 + r);
    }
    #pragma unroll
    for (int mi = 0; mi < 2; mi++)
        #pragma unroll
        for (int nd = 0; nd < 8; nd++) {
            int col = (kvg*4 + hl)*HD + nd*16 + l15;
            #pragma unroll
            for (int r = 0; r < 4; r++) {
                int row = qb + mi*16 + lq*4 + r;
                O[(size_t)row*DIM + col] = f2bf(o_acc[mi][nd][r] * rec[mi][r]);
            }
        }
}

// ---------------------------------------------------------------------------
extern "C" void kernel_launch(void* const* d_in, const int* in_sizes, int n_in,
                              void* d_out, int out_size, void* d_ws, size_t ws_size,
                              hipStream_t stream) {
    const float* x    = (const float*)d_in[0];
    const float* fc   = (const float*)d_in[1];
    const float* fs   = (const float*)d_in[2];
    // d_in[3] mask: causal, analytic. d_in[4,5] caches: dead (pos=0).
    const float* wk_w = (const float*)d_in[6];
    const float* wk_b = (const float*)d_in[7];
    const float* wv_w = (const float*)d_in[8];
    const float* wv_b = (const float*)d_in[9];
    const float* wo_w = (const float*)d_in[10];
    const float* wo_b = (const float*)d_in[11];
    float* out = (float*)d_out;

    short* xb  = (short*)d_ws;                 //  8388608
    short* wkb = xb  + 8388608;                //  4194304
    short* wvb = wkb + 4194304;                //  4194304
    short* wob = wvb + 4194304;                // 16777216
    short* Q   = wob + 16777216;               //  8388608
    short* K   = Q   + 8388608;                //  2097152
    short* V   = K   + 2097152;                //  2097152
    short* Vt  = V   + 2097152;                //  2097152
    short* AO  = Vt  + 2097152;                //  8388608  (total ~113.4 MB)

    cvt_bf16<<<dim3(16384), dim3(256), 0, stream>>>(x, wk_w, wv_w, wo_w, xb, wkb, wvb, wob);

    // fused Q/K/V projections (reference quirk: q is projected with wo_w/wo_b)
    gemm_qkv<<<dim3(48, 16), dim3(256), 0, stream>>>(
        xb, wob, wo_b, Q, wkb, wk_b, K, wvb, wv_b, V);

    int nrope = T_SEQ*NH*(HD/2) + T_SEQ*NKV*(HD/2);
    rope_k<<<dim3((nrope + 255)/256), dim3(256), 0, stream>>>(Q, K, fc, fs);

    vtrans<<<dim3(32, 16), dim3(256), 0, stream>>>(V, Vt);

    flash_attn<<<dim3(64, 8), dim3(256), 0, stream>>>(Q, K, Vt, AO);

    gemm_bt<true><<<dim3(32, 16), dim3(256), 0, stream>>>(AO, wob, wo_b, out, DIM, DIM);
}

// Round 7
// 482.665 us; speedup vs baseline: 1.2344x; 1.0096x over previous
//
#include <hip/hip_runtime.h>
#include <stdint.h>
#include <stddef.h>

#define T_SEQ 2048
#define DIM   4096
#define NH    32
#define NKV   8
#define HD    128
#define KVD   (NKV*HD)   // 1024

typedef __attribute__((ext_vector_type(8))) short short8;
typedef __attribute__((ext_vector_type(4))) float floatx4;
typedef __attribute__((ext_vector_type(2))) unsigned int uintx2;

static __device__ __forceinline__ float bf2f(short u) {
    union { unsigned int i; float f; } c; c.i = ((unsigned int)(unsigned short)u) << 16; return c.f;
}
static __device__ __forceinline__ short f2bf(float f) {
    union { float f; unsigned int u; } c; c.f = f;
    unsigned int r = c.u + 0x7fff + ((c.u >> 16) & 1);
    return (short)(r >> 16);
}
static __device__ __forceinline__ short8 ld8_f2b(const float* p) {
    floatx4 a = *(const floatx4*)p;
    floatx4 b = *(const floatx4*)(p + 4);
    short8 r;
    r[0]=f2bf(a[0]); r[1]=f2bf(a[1]); r[2]=f2bf(a[2]); r[3]=f2bf(a[3]);
    r[4]=f2bf(b[0]); r[5]=f2bf(b[1]); r[6]=f2bf(b[2]); r[7]=f2bf(b[3]);
    return r;
}

// async 16B global->LDS (m97 pattern; LDS dest is wave-uniform-base + lane*16)
#define GLD16(g, l) __builtin_amdgcn_global_load_lds( \
    (const __attribute__((address_space(1))) unsigned int*)(g), \
    (__attribute__((address_space(3))) unsigned int*)(l), 16, 0, 0)

// ---------------------------------------------------------------------------
// fp32 -> bf16 bulk convert: x (8M), wk (4M), wv (4M), wo (16M); 8 elems/thread
// ---------------------------------------------------------------------------
__global__ __launch_bounds__(256)
void cvt_bf16(const float* __restrict__ x, const float* __restrict__ wk,
              const float* __restrict__ wv, const float* __restrict__ wo,
              short* __restrict__ xb, short* __restrict__ wkb,
              short* __restrict__ wvb, short* __restrict__ wob) {
    size_t i8 = ((size_t)blockIdx.x * 256 + threadIdx.x) * 8;
    const float* src; short* dst; size_t off;
    if (i8 < 8388608)        { src = x;  dst = xb;  off = i8; }
    else if (i8 < 12582912)  { src = wk; dst = wkb; off = i8 - 8388608; }
    else if (i8 < 16777216)  { src = wv; dst = wvb; off = i8 - 12582912; }
    else                     { src = wo; dst = wob; off = i8 - 16777216; }
    *(short8*)(dst + off) = ld8_f2b(src + off);
}

// ---------------------------------------------------------------------------
// 8-wave phase-split GEMM (T2+T3+T4+T5 adapted to BM=128, BN=256, BK=64):
// C[M,N] = A[M,K]*B[N,K]^T + bias. 512 threads = 8 waves (2M x 4N), per-wave
// 64x64 output. 2 LDS K-tile buffers (96 KB), staged via global_load_lds
// with chunk-XOR swizzle on the GLOBAL source (slot = chunk ^ (row&7), LDS
// dest linear — rule #21); same XOR on the ds_read side -> 2 lanes/bank
// (free, m136). Per K-tile: {12 ds_read -> lgkmcnt(0) -> 16 MFMA} then
// {4 ds_read -> lgkmcnt(0) -> barrier -> stage next K-tile -> 16 MFMA}.
// vmcnt(6) at iteration top (next tile's 6 loads stay in flight); drained
// only on the final iteration. setprio(1) around MFMA clusters (T5).
// ---------------------------------------------------------------------------
template<bool C_F32>
__global__ __launch_bounds__(512, 1)
void gemm8p(const short* __restrict__ A, const short* __restrict__ B,
            const float* __restrict__ bias, void* __restrict__ Cp,
            int N, int K) {
    __shared__ short sA[2][128*64];
    __shared__ short sB[2][256*64];
    const int tid  = threadIdx.x;
    const int wave = tid >> 6, lane = tid & 63;
    const int l15  = lane & 15, lq = lane >> 4;
    const int sw   = l15 & 7;
    const int wm   = (wave >> 2) * 64;    // 0 / 64
    const int wn   = (wave & 3) * 64;     // 0..192
    const int bm   = blockIdx.y * 128, bn = blockIdx.x * 256;

    floatx4 acc[4][4];
    #pragma unroll
    for (int i = 0; i < 4; i++)
        #pragma unroll
        for (int j = 0; j < 4; j++)
            acc[i][j] = (floatx4)(0.0f);

    // staging maps (chunk c -> lds elem c*8, lane-linear; source pre-swizzled)
    const short* pa[2]; int ca[2];
    #pragma unroll
    for (int i = 0; i < 2; i++) {
        int c = i*512 + tid, row = c >> 3, jg = (c & 7) ^ (row & 7);
        pa[i] = A + (size_t)(bm + row) * K + jg*8;
        ca[i] = c;
    }
    const short* pb[4]; int cb[4];
    #pragma unroll
    for (int i = 0; i < 4; i++) {
        int c = i*512 + tid, row = c >> 3, jg = (c & 7) ^ (row & 7);
        pb[i] = B + (size_t)(bn + row) * K + jg*8;
        cb[i] = c;
    }
    auto stage = [&](int buf, int kt) {
        #pragma unroll
        for (int i = 0; i < 2; i++) GLD16(pa[i] + kt, &sA[buf][ca[i]*8]);
        #pragma unroll
        for (int i = 0; i < 4; i++) GLD16(pb[i] + kt, &sB[buf][cb[i]*8]);
    };

    // prologue: tiles 0 and 1 in flight (12 loads/thread outstanding)
    stage(0, 0);
    stage(1, 64);

    const int nt = K >> 6;   // K-tiles of 64
    int buf = 0;
    for (int t = 0; t < nt; ++t) {
        if (t < nt - 1) asm volatile("s_waitcnt vmcnt(6)" ::: "memory");
        else            asm volatile("s_waitcnt vmcnt(0)" ::: "memory");
        __builtin_amdgcn_s_barrier();        // this K-tile fully landed, all waves

        const short* lA = sA[buf];
        const short* lB = sB[buf];
        short8 af[4][2], bf[4][2];
        // phase 1: A (8) + B n-half 0 (4) = 12 ds_read_b128
        #pragma unroll
        for (int mi = 0; mi < 4; mi++)
            #pragma unroll
            for (int ks = 0; ks < 2; ks++)
                af[mi][ks] = *(const short8*)&lA[(wm + mi*16 + l15)*64
                                                 + (((ks*4 + lq) ^ sw)*8)];
        #pragma unroll
        for (int ni = 0; ni < 2; ni++)
            #pragma unroll
            for (int ks = 0; ks < 2; ks++)
                bf[ni][ks] = *(const short8*)&lB[(wn + ni*16 + l15)*64
                                                 + (((ks*4 + lq) ^ sw)*8)];
        asm volatile("s_waitcnt lgkmcnt(0)" ::: "memory");
        __builtin_amdgcn_sched_barrier(0);
        __builtin_amdgcn_s_setprio(1);
        #pragma unroll
        for (int ks = 0; ks < 2; ks++)
            #pragma unroll
            for (int mi = 0; mi < 4; mi++)
                #pragma unroll
                for (int ni = 0; ni < 2; ni++)
                    acc[mi][ni] = __builtin_amdgcn_mfma_f32_16x16x32_bf16(
                        af[mi][ks], bf[ni][ks], acc[mi][ni], 0, 0, 0);
        __builtin_amdgcn_s_setprio(0);

        // phase 2: B n-half 1 (4 ds_read_b128)
        #pragma unroll
        for (int ni = 2; ni < 4; ni++)
            #pragma unroll
            for (int ks = 0; ks < 2; ks++)
                bf[ni][ks] = *(const short8*)&lB[(wn + ni*16 + l15)*64
                                                 + (((ks*4 + lq) ^ sw)*8)];
        asm volatile("s_waitcnt lgkmcnt(0)" ::: "memory");
        __builtin_amdgcn_sched_barrier(0);
        __builtin_amdgcn_s_barrier();        // all waves done READING this buf
        if (t + 2 < nt) stage(buf, (t + 2) << 6);   // restage; flies across next tile
        __builtin_amdgcn_s_setprio(1);
        #pragma unroll
        for (int ks = 0; ks < 2; ks++)
            #pragma unroll
            for (int mi = 0; mi < 4; mi++)
                #pragma unroll
                for (int ni = 2; ni < 4; ni++)
                    acc[mi][ni] = __builtin_amdgcn_mfma_f32_16x16x32_bf16(
                        af[mi][ks], bf[ni][ks], acc[mi][ni], 0, 0, 0);
        __builtin_amdgcn_s_setprio(0);
        buf ^= 1;
    }

    // epilogue: C/D layout col=lane&15, row=(lane>>4)*4+reg  [m89/m91]
    #pragma unroll
    for (int ni = 0; ni < 4; ni++) {
        int col = bn + wn + ni*16 + l15;
        float bv = bias[col];
        #pragma unroll
        for (int mi = 0; mi < 4; mi++) {
            int row = bm + wm + mi*16 + lq*4;
            #pragma unroll
            for (int r = 0; r < 4; r++) {
                float v = acc[mi][ni][r] + bv;
                if (C_F32) ((float*)Cp)[(size_t)(row + r)*N + col] = v;
                else       ((short*)Cp)[(size_t)(row + r)*N + col] = f2bf(v);
            }
        }
    }
}

// ---------------------------------------------------------------------------
// Counted-vmcnt 128x128 GEMM core (r6, known-good) — used for the K/V
// projections (N=1024 each; grid 256 blocks).
// ---------------------------------------------------------------------------
template<bool C_F32>
static __device__ __forceinline__
void gemm_core(const short* __restrict__ A, const short* __restrict__ B,
               const float* __restrict__ bias, void* __restrict__ Cp,
               int N, int K, int bm, int bn) {
    __shared__ short sA0[128*32];
    __shared__ short sA1[128*32];
    __shared__ short sA2[128*32];
    __shared__ short sB0[128*32];
    __shared__ short sB1[128*32];
    __shared__ short sB2[128*32];
    const int tid  = threadIdx.x;
    const int wave = tid >> 6, lane = tid & 63;
    const int l15  = lane & 15, lq = lane >> 4;
    const int wm   = (wave >> 1) * 64, wn = (wave & 1) * 64;

    floatx4 acc[4][4];
    #pragma unroll
    for (int i = 0; i < 4; i++)
        #pragma unroll
        for (int j = 0; j < 4; j++)
            acc[i][j] = (floatx4)(0.0f);

    const int c0 = tid, c1 = 256 + tid;
    const int r0 = c0 >> 2, k0 = (c0 & 3) * 8;
    const int r1 = c1 >> 2, k1 = (c1 & 3) * 8;
    const short* pA0 = A + (size_t)(bm + r0) * K + k0;
    const short* pA1 = A + (size_t)(bm + r1) * K + k1;
    const short* pB0 = B + (size_t)(bn + r0) * K + k0;
    const short* pB1 = B + (size_t)(bn + r1) * K + k1;

    auto stage = [&](short* dA, short* dB, int kt) {
        GLD16(pA0 + kt, dA + c0 * 8);
        GLD16(pA1 + kt, dA + c1 * 8);
        GLD16(pB0 + kt, dB + c0 * 8);
        GLD16(pB1 + kt, dB + c1 * 8);
    };
    auto compute = [&](const short* dA, const short* dB) {
        short8 af[4], bfr[4];
        #pragma unroll
        for (int mi = 0; mi < 4; mi++)
            af[mi] = *(const short8*)&dA[(wm + mi*16 + l15)*32 + lq*8];
        #pragma unroll
        for (int ni = 0; ni < 4; ni++)
            bfr[ni] = *(const short8*)&dB[(wn + ni*16 + l15)*32 + lq*8];
        #pragma unroll
        for (int mi = 0; mi < 4; mi++)
            #pragma unroll
            for (int ni = 0; ni < 4; ni++)
                acc[mi][ni] = __builtin_amdgcn_mfma_f32_16x16x32_bf16(af[mi], bfr[ni], acc[mi][ni], 0, 0, 0);
    };

    stage(sA0, sB0, 0);
    stage(sA1, sB1, 32);
    short *cA = sA0, *cB = sB0;
    short *nA = sA1, *nB = sB1;
    short *fA = sA2, *fB = sB2;

    const int nt = K >> 5;
    for (int t = 0; t < nt - 1; ++t) {
        asm volatile("s_waitcnt vmcnt(4)" ::: "memory");
        __builtin_amdgcn_s_barrier();
        if (t + 2 < nt) stage(fA, fB, (t + 2) * 32);
        compute(cA, cB);
        short* x;
        x = cA; cA = nA; nA = fA; fA = x;
        x = cB; cB = nB; nB = fB; fB = x;
    }
    asm volatile("s_waitcnt vmcnt(0)" ::: "memory");
    __builtin_amdgcn_s_barrier();
    compute(cA, cB);

    #pragma unroll
    for (int ni = 0; ni < 4; ni++) {
        int col = bn + wn + ni*16 + l15;
        float bv = bias[col];
        #pragma unroll
        for (int mi = 0; mi < 4; mi++) {
            int row = bm + wm + mi*16 + lq*4;
            #pragma unroll
            for (int r = 0; r < 4; r++) {
                float v = acc[mi][ni][r] + bv;
                if (C_F32) ((float*)Cp)[(size_t)(row + r)*N + col] = v;
                else       ((short*)Cp)[(size_t)(row + r)*N + col] = f2bf(v);
            }
        }
    }
}

// K and V projections fused into one dispatch (z selects), 256 blocks total
__global__ __launch_bounds__(256)
void gemm_kv(const short* __restrict__ A,
             const short* __restrict__ Bk, const float* __restrict__ bk, short* __restrict__ Ck,
             const short* __restrict__ Bv, const float* __restrict__ bv, short* __restrict__ Cv) {
    const short* B = blockIdx.z ? Bv : Bk;
    const float* bias = blockIdx.z ? bv : bk;
    short* C = blockIdx.z ? Cv : Ck;
    gemm_core<false>(A, B, bias, C, KVD, DIM, blockIdx.y * 128, blockIdx.x * 128);
}

// ---------------------------------------------------------------------------
// RoPE in-place on bf16 Q (T,NH,HD) and K (T,NKV,HD); freqs fp32.
// Q is additionally pre-scaled by 1/sqrt(HD) * log2(e): flash_attn's softmax
// then runs in base-2 (exp2 = native v_exp_f32), no per-element scale muls.
// ---------------------------------------------------------------------------
#define QSC (0.08838834764831845f * 1.4426950408889634f)

__global__ __launch_bounds__(256)
void rope_k(short* __restrict__ Q, short* __restrict__ Kc,
            const float* __restrict__ fc, const float* __restrict__ fs) {
    int idx = blockIdx.x * 256 + threadIdx.x;
    const int NQ = T_SEQ * NH  * (HD/2);
    const int NK = T_SEQ * NKV * (HD/2);
    short* base; int t, i; size_t off; float sc;
    if (idx < NQ) {
        i = idx & 63;
        int th = idx >> 6;
        t = th >> 5;
        off = (size_t)th * HD + i*2;
        base = Q; sc = QSC;
    } else if (idx < NQ + NK) {
        int kidx = idx - NQ;
        i = kidx & 63;
        int th = kidx >> 6;
        t = th >> 3;
        off = (size_t)th * HD + i*2;
        base = Kc; sc = 1.0f;
    } else return;
    float re = bf2f(base[off]), im = bf2f(base[off+1]);
    float c = fc[t*64 + i], s = fs[t*64 + i];
    base[off]   = f2bf((re*c - im*s)*sc);
    base[off+1] = f2bf((re*s + im*c)*sc);
}

// ---------------------------------------------------------------------------
// V[T,KVD] -> Vt[KVD,T]  (64x64 LDS tiles)
// ---------------------------------------------------------------------------
__global__ __launch_bounds__(256)
void vtrans(const short* __restrict__ V, short* __restrict__ Vt) {
    __shared__ short sT[64*72];
    const int tid = threadIdx.x;
    const int bt = blockIdx.x, bd = blockIdx.y;
    #pragma unroll
    for (int i = 0; i < 2; i++) {
        int c = i*256 + tid;
        int r = c >> 3, c8 = (c & 7) * 8;
        *(short8*)&sT[r*72 + c8] = *(const short8*)(V + (size_t)(bt*64 + r)*KVD + bd*64 + c8);
    }
    __syncthreads();
    #pragma unroll
    for (int i = 0; i < 2; i++) {
        int c = i*256 + tid;
        int d = c >> 3, t8 = (c & 7) * 8;
        short8 o;
        #pragma unroll
        for (int j = 0; j < 8; j++) o[j] = sT[(t8 + j)*72 + d];
        *(short8*)(Vt + (size_t)(bd*64 + d)*T_SEQ + bt*64 + t8) = o;
    }
}

// ---------------------------------------------------------------------------
// Causal flash attention, kv-grouped: grid (64, 8), block 256 (4 waves).
// (unchanged from round 5 — swapped QK^T, base-2 softmax, 2-phase staging)
// ---------------------------------------------------------------------------
__global__ __launch_bounds__(256, 2)
void flash_attn(const short* __restrict__ Q, const short* __restrict__ Kc,
                const short* __restrict__ Vt, short* __restrict__ O) {
    __shared__ short sK0[64*128];
    __shared__ short sK1[64*128];
    __shared__ short sV0[128*64];     // [d][k]
    __shared__ short sV1[128*64];
    __shared__ short sP[4*2048];      // per-wave 32q x 64k strip (128 B rows)
    const int tid  = threadIdx.x;
    const int wave = tid >> 6, lane = tid & 63;
    const int l15  = lane & 15, lq = lane >> 4;
    const int sw   = l15 & 7;            // row-keyed XOR (row&7 == l15&7 here)
    const int kvg  = blockIdx.y;
    const int qt   = (blockIdx.y < 4) ? (int)blockIdx.x : 63 - (int)blockIdx.x;
    const int hl   = wave;               // head_local 0..3
    const int qb   = qt * 32;

    short8 qf[2][4];
    #pragma unroll
    for (int mi = 0; mi < 2; mi++)
        #pragma unroll
        for (int ks = 0; ks < 4; ks++)
            qf[mi][ks] = *(const short8*)(Q + (size_t)(qb + mi*16 + l15)*DIM
                                          + kvg*512 + hl*128 + ks*32 + lq*8);

    char* pw = (char*)(sP + wave*2048);   // wave-private 4 KB

    int kc_r[4], kc_jg[4], vc_r[4], vc_jg[4];
    #pragma unroll
    for (int i = 0; i < 4; i++) {
        int c = i*256 + tid;
        kc_r[i]  = c >> 4;
        kc_jg[i] = (c & 15) ^ (kc_r[i] & 7);
        vc_r[i]  = c >> 3;
        vc_jg[i] = (c & 7) ^ (vc_r[i] & 7);
    }
    auto stage = [&](short* dK, short* dV, int kt) {
        #pragma unroll
        for (int i = 0; i < 4; i++) {
            int c = i*256 + tid;
            GLD16(Kc + (size_t)(kt*64 + kc_r[i])*KVD + kvg*HD + kc_jg[i]*8,
                  dK + c*8);
            GLD16(Vt + (size_t)(kvg*HD + vc_r[i])*T_SEQ + kt*64 + vc_jg[i]*8,
                  dV + c*8);
        }
    };

    float m_r[2] = {-1e30f, -1e30f};     // stats layout: lane holds q = mi*16+l15
    float l_r[2] = {0.0f, 0.0f};
    floatx4 o_acc[2][8];                 // acc layout: rows q = lq*4+r, col d = l15
    #pragma unroll
    for (int mi = 0; mi < 2; mi++)
        #pragma unroll
        for (int nd = 0; nd < 8; nd++) o_acc[mi][nd] = (floatx4)(0.0f);

    const int ktmax = qt >> 1;
    stage(sK0, sV0, 0);              // prologue
    __syncthreads();                 // implicit vmcnt(0) drains prologue loads

    for (int kt = 0; kt <= ktmax; kt++) {
        short* bK = (kt & 1) ? sK1 : sK0;
        short* bV = (kt & 1) ? sV1 : sV0;
        if (kt < ktmax) stage((kt & 1) ? sK0 : sK1, (kt & 1) ? sV0 : sV1, kt + 1);

        floatx4 s_acc[2][4];
        #pragma unroll
        for (int mi = 0; mi < 2; mi++)
            #pragma unroll
            for (int ni = 0; ni < 4; ni++) s_acc[mi][ni] = (floatx4)(0.0f);
        __builtin_amdgcn_s_setprio(1);
        #pragma unroll
        for (int ks = 0; ks < 4; ks++)
            #pragma unroll
            for (int ni = 0; ni < 4; ni++) {
                short8 kf = *(const short8*)&bK[(ni*16 + l15)*128
                                                + (((ks*4 + lq) ^ sw)*8)];
                s_acc[0][ni] = __builtin_amdgcn_mfma_f32_16x16x32_bf16(kf, qf[0][ks], s_acc[0][ni], 0, 0, 0);
                s_acc[1][ni] = __builtin_amdgcn_mfma_f32_16x16x32_bf16(kf, qf[1][ks], s_acc[1][ni], 0, 0, 0);
            }
        __builtin_amdgcn_s_setprio(0);

        const bool last = (kt == ktmax);

        #pragma unroll
        for (int mi = 0; mi < 2; mi++) {
            float sv[4][4];
            float mx = -1e30f;
            const int qrow = qb + mi*16 + l15;
            #pragma unroll
            for (int ni = 0; ni < 4; ni++)
                #pragma unroll
                for (int r = 0; r < 4; r++) {
                    float x = s_acc[mi][ni][r];
                    if (last) {
                        int kcol = kt*64 + ni*16 + lq*4 + r;
                        x = (kcol <= qrow) ? x : -1e30f;
                    }
                    sv[ni][r] = x;
                    mx = fmaxf(mx, x);
                }
            mx = fmaxf(mx, __shfl_xor(mx, 16));
            mx = fmaxf(mx, __shfl_xor(mx, 32));

            if (__any(mx - m_r[mi] > 8.0f)) {
                float mn = fmaxf(m_r[mi], mx);
                float a  = __builtin_amdgcn_exp2f(m_r[mi] - mn);
                m_r[mi] = mn;
                l_r[mi] *= a;
                float ar[4];
                #pragma unroll
                for (int r = 0; r < 4; r++) ar[r] = __shfl(a, lq*4 + r);
                #pragma unroll
                for (int nd = 0; nd < 8; nd++)
                    #pragma unroll
                    for (int r = 0; r < 4; r++) o_acc[mi][nd][r] *= ar[r];
            }

            float rs = 0.0f;
            #pragma unroll
            for (int ni = 0; ni < 4; ni++)
                #pragma unroll
                for (int r = 0; r < 4; r++) {
                    float p = __builtin_amdgcn_exp2f(sv[ni][r] - m_r[mi]);
                    sv[ni][r] = p;
                    rs += p;
                }
            rs += __shfl_xor(rs, 16);
            rs += __shfl_xor(rs, 32);
            l_r[mi] += rs;

            char* rowp = pw + (mi*16 + l15)*128 + (lq & 1)*8;
            #pragma unroll
            for (int ni = 0; ni < 4; ni++) {
                unsigned int lo, hi;
                asm("v_cvt_pk_bf16_f32 %0, %1, %2" : "=v"(lo) : "v"(sv[ni][0]), "v"(sv[ni][1]));
                asm("v_cvt_pk_bf16_f32 %0, %1, %2" : "=v"(hi) : "v"(sv[ni][2]), "v"(sv[ni][3]));
                int kc = ni*2 + (lq >> 1);
                *(uintx2*)(rowp + ((kc ^ sw) * 16)) = (uintx2){lo, hi};
            }
        }

        __builtin_amdgcn_s_setprio(1);
        #pragma unroll
        for (int ks = 0; ks < 2; ks++) {
            short8 pf[2];
            #pragma unroll
            for (int mi = 0; mi < 2; mi++)
                pf[mi] = *(const short8*)(pw + (mi*16 + l15)*128
                                          + (((ks*4 + lq) ^ sw)*16));
            #pragma unroll
            for (int nd = 0; nd < 8; nd++) {
                short8 vf = *(const short8*)&bV[(nd*16 + l15)*64
                                                + (((ks*4 + lq) ^ sw)*8)];
                o_acc[0][nd] = __builtin_amdgcn_mfma_f32_16x16x32_bf16(pf[0], vf, o_acc[0][nd], 0, 0, 0);
                o_acc[1][nd] = __builtin_amdgcn_mfma_f32_16x16x32_bf16(pf[1], vf, o_acc[1][nd], 0, 0, 0);
            }
        }
        __builtin_amdgcn_s_setprio(0);

        __syncthreads();
    }

    float rec[2][4];
    #pragma unroll
    for (int mi = 0; mi < 2; mi++) {
        float rv = 1.0f / l_r[mi];
        #pragma unroll
        for (int r = 0; r < 4; r++) rec[mi][r] = __shfl(rv, lq*4 + r);
    }
    #pragma unroll
    for (int mi = 0; mi < 2; mi++)
        #pragma unroll
        for (int nd = 0; nd < 8; nd++) {
            int col = (kvg*4 + hl)*HD + nd*16 + l15;
            #pragma unroll
            for (int r = 0; r < 4; r++) {
                int row = qb + mi*16 + lq*4 + r;
                O[(size_t)row*DIM + col] = f2bf(o_acc[mi][nd][r] * rec[mi][r]);
            }
        }
}

// ---------------------------------------------------------------------------
extern "C" void kernel_launch(void* const* d_in, const int* in_sizes, int n_in,
                              void* d_out, int out_size, void* d_ws, size_t ws_size,
                              hipStream_t stream) {
    const float* x    = (const float*)d_in[0];
    const float* fc   = (const float*)d_in[1];
    const float* fs   = (const float*)d_in[2];
    // d_in[3] mask: causal, analytic. d_in[4,5] caches: dead (pos=0).
    const float* wk_w = (const float*)d_in[6];
    const float* wk_b = (const float*)d_in[7];
    const float* wv_w = (const float*)d_in[8];
    const float* wv_b = (const float*)d_in[9];
    const float* wo_w = (const float*)d_in[10];
    const float* wo_b = (const float*)d_in[11];
    float* out = (float*)d_out;

    short* xb  = (short*)d_ws;                 //  8388608
    short* wkb = xb  + 8388608;                //  4194304
    short* wvb = wkb + 4194304;                //  4194304
    short* wob = wvb + 4194304;                // 16777216
    short* Q   = wob + 16777216;               //  8388608
    short* K   = Q   + 8388608;                //  2097152
    short* V   = K   + 2097152;                //  2097152
    short* Vt  = V   + 2097152;                //  2097152
    short* AO  = Vt  + 2097152;                //  8388608  (total ~113.4 MB)

    cvt_bf16<<<dim3(16384), dim3(256), 0, stream>>>(x, wk_w, wv_w, wo_w, xb, wkb, wvb, wob);

    // Q projection (reference quirk: q uses wo_w/wo_b): 8-wave phase-split
    gemm8p<false><<<dim3(16, 16), dim3(512), 0, stream>>>(xb, wob, wo_b, Q, DIM, DIM);
    // K/V projections on the 128x128 core
    gemm_kv<<<dim3(8, 16, 2), dim3(256), 0, stream>>>(xb, wkb, wk_b, K, wvb, wv_b, V);

    int nrope = T_SEQ*NH*(HD/2) + T_SEQ*NKV*(HD/2);
    rope_k<<<dim3((nrope + 255)/256), dim3(256), 0, stream>>>(Q, K, fc, fs);

    vtrans<<<dim3(32, 16), dim3(256), 0, stream>>>(V, Vt);

    flash_attn<<<dim3(64, 8), dim3(256), 0, stream>>>(Q, K, Vt, AO);

    // out projection: 8-wave phase-split, f32 output
    gemm8p<true><<<dim3(16, 16), dim3(512), 0, stream>>>(AO, wob, wo_b, out, DIM, DIM);
}